// Round 12
// baseline (513.349 us; speedup 1.0000x reference)
//
#include <hip/hip_runtime.h>
#include <cstdint>
#include <cstddef>

typedef unsigned short u16;
typedef __attribute__((ext_vector_type(8))) short bf16x8;
typedef __attribute__((ext_vector_type(4))) float f32x4;

#define MFMA32(a, b, c) __builtin_amdgcn_mfma_f32_16x16x32_bf16(a, b, c, 0, 0, 0)

__device__ __forceinline__ u16 f2b(float f) {
  union { float f; unsigned u; } v; v.f = f;
  unsigned u = v.u;
  return (u16)((u + 0x7fffu + ((u >> 16) & 1u)) >> 16);
}
__device__ __forceinline__ float b2f(u16 h) {
  union { unsigned u; float f; } v; v.u = ((unsigned)h) << 16;
  return v.f;
}

// async global->LDS, 16B per lane. LDS dest must be wave-uniform base + lane*16.
__device__ __forceinline__ void g2l16(const void* g, void* l) {
  __builtin_amdgcn_global_load_lds((__attribute__((address_space(1))) void*)(g),
                                   (__attribute__((address_space(3))) void*)(l), 16, 0, 0);
}

// ---------------- ALL fp32->bf16 casts in one launch --------------------------
__global__ __launch_bounds__(256) void cast_all(const float* __restrict__ x,
                                                const float* __restrict__ W0,
                                                const float* __restrict__ W1,
                                                const float* __restrict__ W2,
                                                const float* __restrict__ W3,
                                                const float* __restrict__ Wv,
                                                const float* __restrict__ Wo,
                                                u16* __restrict__ xb,
                                                u16* __restrict__ Wall,
                                                u16* __restrict__ Wob) {
  const int blk = blockIdx.x;
  const float* src;
  u16* dst;
  int li;
  if (blk < 8192) {
    src = x; dst = xb; li = blk * 256 + threadIdx.x;
  } else if (blk < 16384) {
    const int s = (blk - 8192) >> 11;
    src = s == 0 ? W0 : s == 1 ? W1 : s == 2 ? W2 : W3;
    dst = Wall + (size_t)s * 2097152;
    li = ((blk - 8192) & 2047) * 256 + threadIdx.x;
  } else if (blk < 20480) {
    src = Wv; dst = Wall + (size_t)4 * 2097152;
    li = (blk - 16384) * 256 + threadIdx.x;
  } else {
    src = Wo; dst = Wob;
    li = (blk - 20480) * 256 + threadIdx.x;
  }
  float4 v = ((const float4*)src)[li];
  ushort4 r;
  r.x = f2b(v.x); r.y = f2b(v.y); r.z = f2b(v.z); r.w = f2b(v.w);
  ((ushort4*)dst)[li] = r;
}

// ---------------- C = A @ B^T  128x128 tile (m97 structure; final projection) -
template <bool BF16_OUT>
__global__ __launch_bounds__(256) void gemm_bt(const u16* __restrict__ A,
                                               const u16* __restrict__ B,
                                               void* __restrict__ C, int N, int K) {
  __shared__ u16 As[128 * 64];
  __shared__ u16 Bs[128 * 64];
  const int tid = threadIdx.x;
  const int wid = tid >> 6;
  const int lane = tid & 63;
  const int lm = lane & 15;
  const int quad = lane >> 4;
  const int r3 = lm & 7;
  const int wm = (wid & 1) * 64;
  const int wn = (wid >> 1) * 64;
  const int bm = blockIdx.y * 128;
  const int bn = blockIdx.x * 128;

  const u16* Ab = A + (size_t)bm * K;
  const u16* Bb = B + (size_t)bn * K;

  f32x4 zero = {0.f, 0.f, 0.f, 0.f};
  f32x4 acc[4][4];
#pragma unroll
  for (int i = 0; i < 4; ++i)
#pragma unroll
    for (int j = 0; j < 4; ++j) acc[i][j] = zero;

  for (int k0 = 0; k0 < K; k0 += 64) {
#pragma unroll
    for (int it = 0; it < 4; ++it) {
      int c = it * 256 + tid;
      int rg = c >> 6, rw = (c >> 3) & 7, u = c & 7;
      int row = rg * 8 + rw;
      int chd = u ^ rw;
      g2l16(Ab + (size_t)row * K + k0 + chd * 8, As + c * 8);
      g2l16(Bb + (size_t)row * K + k0 + chd * 8, Bs + c * 8);
    }
    __syncthreads();
#pragma unroll
    for (int ks = 0; ks < 2; ++ks) {
      bf16x8 a[4], b[4];
      int chd = ks * 4 + quad;
#pragma unroll
      for (int i = 0; i < 4; ++i) {
        int row = wm + i * 16 + lm;
        a[i] = *(const bf16x8*)(As + (((row >> 3) * 64 + r3 * 8 + (chd ^ r3)) * 8));
      }
#pragma unroll
      for (int j = 0; j < 4; ++j) {
        int row = wn + j * 16 + lm;
        b[j] = *(const bf16x8*)(Bs + (((row >> 3) * 64 + r3 * 8 + (chd ^ r3)) * 8));
      }
#pragma unroll
      for (int i = 0; i < 4; ++i)
#pragma unroll
        for (int j = 0; j < 4; ++j)
          acc[i][j] = MFMA32(a[i], b[j], acc[i][j]);
    }
    __syncthreads();
  }

#pragma unroll
  for (int i = 0; i < 4; ++i)
#pragma unroll
    for (int j = 0; j < 4; ++j)
#pragma unroll
      for (int r = 0; r < 4; ++r) {
        int row = bm + wm + i * 16 + quad * 4 + r;
        int col = bn + wn + j * 16 + lm;
        float v = acc[i][j][r];
        if (BF16_OUT)
          ((u16*)C)[(size_t)row * N + col] = f2b(v);
        else
          ((float*)C)[(size_t)row * N + col] = v;
      }
}

// ---------------- QKV GEMM with fused RoPE/rearrange epilogue v3 (hybrid) -----
__global__ __launch_bounds__(256) void gemm_qkv(const u16* __restrict__ A,
                                                const u16* __restrict__ B,
                                                u16* __restrict__ Qb,
                                                u16* __restrict__ Kb,
                                                u16* __restrict__ VT) {
  constexpr int K = 2048;
  const float SC = 0.12751744f;  // (1/sqrt(128)) * log2(e)
  __shared__ u16 sh[16384];      // As | Bs, reused for V staging
  u16* As = sh;
  u16* Bs = sh + 8192;
  const int tid = threadIdx.x;
  const int wid = tid >> 6;
  const int lane = tid & 63;
  const int lm = lane & 15;
  const int quad = lane >> 4;
  const int r3 = lm & 7;
  const int wm = (wid & 1) * 64;
  const int wn = (wid >> 1) * 64;
  const int bm = blockIdx.y * 128;
  const int bn = blockIdx.x * 128;

  const u16* Ab = A + (size_t)bm * K;
  const u16* Bb = B + (size_t)bn * K;

  f32x4 zero = {0.f, 0.f, 0.f, 0.f};
  f32x4 acc[4][4];
#pragma unroll
  for (int i = 0; i < 4; ++i)
#pragma unroll
    for (int j = 0; j < 4; ++j) acc[i][j] = zero;

  for (int k0 = 0; k0 < K; k0 += 64) {
#pragma unroll
    for (int it = 0; it < 4; ++it) {
      int c = it * 256 + tid;
      int rg = c >> 6, rw = (c >> 3) & 7, u = c & 7;
      int row = rg * 8 + rw;
      int chd = u ^ rw;
      g2l16(Ab + (size_t)row * K + k0 + chd * 8, As + c * 8);
      g2l16(Bb + (size_t)row * K + k0 + chd * 8, Bs + c * 8);
    }
    __syncthreads();
#pragma unroll
    for (int ks = 0; ks < 2; ++ks) {
      bf16x8 a[4], b[4];
      int chd = ks * 4 + quad;
#pragma unroll
      for (int i = 0; i < 4; ++i) {
        int row = wm + i * 16 + lm;
        a[i] = *(const bf16x8*)(As + (((row >> 3) * 64 + r3 * 8 + (chd ^ r3)) * 8));
      }
#pragma unroll
      for (int j = 0; j < 4; ++j) {
        int row = wn + j * 16 + lm;
        b[j] = *(const bf16x8*)(Bs + (((row >> 3) * 64 + r3 * 8 + (chd ^ r3)) * 8));
      }
#pragma unroll
      for (int i = 0; i < 4; ++i)
#pragma unroll
        for (int j = 0; j < 4; ++j)
          acc[i][j] = MFMA32(a[i], b[j], acc[i][j]);
    }
    __syncthreads();
  }

  const int seg = bn >> 10;       // uniform per block
  const int b = bm >> 11;
  const int sbase = bm & 2047;
  const int h = ((bn + wn) >> 6) & 15;  // head for Q/K segments
  const size_t bhQ = (size_t)b * 16 + h;

  if (seg < 2) {
    // ---- sem: direct copy ----
    u16* dst = (seg == 0) ? Qb : Kb;
    const float sc = (seg == 0) ? SC : 1.0f;
#pragma unroll
    for (int i = 0; i < 4; ++i)
#pragma unroll
      for (int r = 0; r < 4; ++r) {
        const int s = sbase + wm + i * 16 + quad * 4 + r;
        u16* base = dst + (bhQ * 2048 + s) * 128;
#pragma unroll
        for (int j = 0; j < 4; ++j) {
          const int d = (wn + j * 16 + lm) & 63;
          base[d] = f2b(acc[i][j][r] * sc);
        }
      }
  } else if (seg < 4) {
    // ---- geo: RoPE in-register, write d in [64,128) ----
    u16* dst = (seg == 2) ? Qb : Kb;
    const float sc = (seg == 2) ? SC : 1.0f;
    const float inv0 = __powf(10000.0f, -(float)(2 * lm) * (1.0f / 64.0f));
    const float inv1 = __powf(10000.0f, -(float)(2 * (16 + lm)) * (1.0f / 64.0f));
#pragma unroll
    for (int i = 0; i < 4; ++i)
#pragma unroll
      for (int r = 0; r < 4; ++r) {
        const int s = sbase + wm + i * 16 + quad * 4 + r;
        float sn0, cs0, sn1, cs1;
        __sincosf((float)s * inv0, &sn0, &cs0);
        __sincosf((float)s * inv1, &sn1, &cs1);
        const float x1a = acc[i][0][r], x2a = acc[i][2][r];  // f0 = lm
        const float x1b = acc[i][1][r], x2b = acc[i][3][r];  // f0 = 16+lm
        u16* base = dst + (bhQ * 2048 + s) * 128 + 64;
        base[lm]      = f2b((x1a * cs0 - x2a * sn0) * sc);
        base[16 + lm] = f2b((x1b * cs1 - x2b * sn1) * sc);
        base[32 + lm] = f2b((x1a * sn0 + x2a * cs0) * sc);
        base[48 + lm] = f2b((x1b * sn1 + x2b * cs1) * sc);
      }
  } else {
    // ---- V: stage TRANSPOSED [d][s] swizzled, write coalesced VT rows -------
    const int hv = (bn - 4096) >> 7;   // one head per tile
    const size_t bh = (size_t)b * 16 + hv;
#pragma unroll
    for (int i = 0; i < 4; ++i)
#pragma unroll
      for (int r = 0; r < 4; ++r) {
        const int sr = wm + i * 16 + quad * 4 + r;
#pragma unroll
        for (int j = 0; j < 4; ++j) {
          const int d = wn + j * 16 + lm;
          sh[d * 128 + (((sr >> 3) ^ (d & 7)) << 3) + (sr & 7)] = f2b(acc[i][j][r]);
        }
      }
    __syncthreads();
#pragma unroll
    for (int it = 0; it < 8; ++it) {
      const int idx = it * 256 + tid;
      const int d = idx >> 4;      // 0..127
      const int ch = idx & 15;     // 8-s chunk
      bf16x8 v = *(const bf16x8*)(sh + d * 128 + ((ch ^ (d & 7)) << 3));
      *(bf16x8*)(VT + (bh * 128 + d) * 2048 + sbase + ch * 8) = v;
    }
  }
}

// ---------------- fused causal attention v11: shared-fragment dual-q ----------
// v10 read every K/V b128 fragment TWICE per iteration (once for q-tile B's
// MFMAs, once for A's) -> ~68 b128/wave/iter = ~800 LDS-pipe cycles vs ~340
// MFMA cycles: LDS-read-BW bound (matches MfmaUtil ~10-15%, all pipes idle).
// v11 fuses the A/B loops: each bk/bv fragment is loaded ONCE and feeds two
// MFMAs. Halves LDS b128 traffic in the dual region (~30% overall). Register
// budget ~166 VGPR, under the 170 cap of launch_bounds(256,3).
__global__ __launch_bounds__(256, 3) void attn_v11(const u16* __restrict__ Q,
                                                   const u16* __restrict__ K,
                                                   const u16* __restrict__ VT,
                                                   u16* __restrict__ O) {
  constexpr int S = 2048;
  constexpr int D = 128;
  __shared__ u16 Ks[64 * 128];   // chunk-swizzled
  __shared__ u16 Vs[128 * 64];   // VT tile [d][s_local], chunk-swizzled
  __shared__ u16 PsA[64 * 72];   // wave-private rows; padded stride 72
  __shared__ u16 PsB[64 * 72];
  const int linear = blockIdx.x + (blockIdx.y << 4);
  const int xcd = linear & 7;
  const int slot = linear >> 3;          // 0..63
  const int bh = (xcd << 2) + (slot >> 4);
  const int bx = slot & 15;
  const int b = bh >> 4, h = bh & 15;
  const int tid = threadIdx.x, wid = tid >> 6, lane = tid & 63;
  const int lm = lane & 15, quad = lane >> 4;
  const int rx = lm & 7;
  const int wrow = wid * 16;

  const int qtA = bx;        // 0..15
  const int qtB = 31 - bx;   // 16..31 (always > qtA)

  const u16* Kbh = K + (size_t)bh * S * D;
  const u16* Vbh = VT + (size_t)bh * D * S;

  const bf16x8 vones = {16256, 16256, 16256, 16256, 16256, 16256, 16256, 16256};  // bf16 1.0

  bf16x8 aqA[4], aqB[4];
#pragma unroll
  for (int ks = 0; ks < 4; ++ks) {
    aqA[ks] = *(const bf16x8*)(Q + ((size_t)bh * S + (size_t)qtA * 64 + wrow + lm) * D +
                               ks * 32 + quad * 8);
    aqB[ks] = *(const bf16x8*)(Q + ((size_t)bh * S + (size_t)qtB * 64 + wrow + lm) * D +
                               ks * 32 + quad * 8);
  }

  f32x4 zero = {0.f, 0.f, 0.f, 0.f};
  f32x4 lsumA = zero, lsumB = zero;
  f32x4 oaccA[8], oaccB[8];
#pragma unroll
  for (int t = 0; t < 8; ++t) { oaccA[t] = zero; oaccB[t] = zero; }

#pragma unroll 1
  for (int kt = 0; kt <= qtB; ++kt) {
    __syncthreads();  // prior iteration's readers done with Ks/Vs
    const u16* Kt = Kbh + (size_t)kt * 64 * D;
    const u16* Vt = Vbh + (size_t)kt * 64;
#pragma unroll
    for (int it = 0; it < 4; ++it) {
      int c = it * 256 + tid;
      int row = c >> 4, u = c & 15;
      g2l16(Kt + (size_t)row * 128 + (size_t)(u ^ (row & 7)) * 8, Ks + c * 8);
    }
#pragma unroll
    for (int it = 0; it < 4; ++it) {
      int c = it * 256 + tid;
      int row = c >> 3, u = c & 7;
      g2l16(Vt + (size_t)row * S + (size_t)(u ^ (row & 7)) * 8, Vs + c * 8);
    }
    __syncthreads();  // barrier drains vmcnt: staged data visible

    if (kt <= qtA) {
      // ======== dual region: each fragment read feeds TWO MFMAs ========
      f32x4 scA[4], scB[4];
#pragma unroll
      for (int j = 0; j < 4; ++j) { scA[j] = zero; scB[j] = zero; }
      __builtin_amdgcn_s_setprio(1);
#pragma unroll
      for (int ks = 0; ks < 4; ++ks) {
        const int kc = ks * 4 + quad;
#pragma unroll
        for (int j = 0; j < 4; ++j) {
          bf16x8 bk = *(const bf16x8*)(Ks + (((j * 16 + lm) * 16 + (kc ^ rx)) * 8));
          scB[j] = MFMA32(aqB[ks], bk, scB[j]);
          scA[j] = MFMA32(aqA[ks], bk, scA[j]);
        }
      }
      __builtin_amdgcn_s_setprio(0);

      const bool diagA = (kt == qtA);
#pragma unroll
      for (int r = 0; r < 4; ++r) {
        const int qcol = wrow + quad * 4 + r;
        const int prow = (wrow + quad * 4 + r) * 72;
#pragma unroll
        for (int j = 0; j < 4; ++j) {
          float pB = __builtin_amdgcn_exp2f(fminf(scB[j][r], 30.0f));
          float pA = __builtin_amdgcn_exp2f(fminf(scA[j][r], 30.0f));
          if (diagA && (j * 16 + lm > qcol)) pA = 0.f;  // diag B impossible here (kt<=qtA<qtB)
          PsB[prow + j * 16 + lm] = f2b(pB);
          PsA[prow + j * 16 + lm] = f2b(pA);
        }
      }
      // no barrier: Ps rows are wave-private (proven R4)

      __builtin_amdgcn_s_setprio(1);
#pragma unroll
      for (int ks = 0; ks < 2; ++ks) {
        bf16x8 apB = *(const bf16x8*)(PsB + (wrow + lm) * 72 + ks * 32 + quad * 8);
        bf16x8 apA = *(const bf16x8*)(PsA + (wrow + lm) * 72 + ks * 32 + quad * 8);
        const int kc = ks * 4 + quad;
        lsumB = MFMA32(apB, vones, lsumB);
        lsumA = MFMA32(apA, vones, lsumA);
#pragma unroll
        for (int t = 0; t < 8; ++t) {
          bf16x8 bv = *(const bf16x8*)(Vs + (((t * 16 + lm) * 8 + (kc ^ rx)) * 8));
          oaccB[t] = MFMA32(apB, bv, oaccB[t]);
          oaccA[t] = MFMA32(apA, bv, oaccA[t]);
        }
      }
      __builtin_amdgcn_s_setprio(0);
    } else {
      // ======== B-only region (kt > qtA) ========
      f32x4 sc[4];
#pragma unroll
      for (int j = 0; j < 4; ++j) sc[j] = zero;
      __builtin_amdgcn_s_setprio(1);
#pragma unroll
      for (int ks = 0; ks < 4; ++ks) {
        const int kc = ks * 4 + quad;
#pragma unroll
        for (int j = 0; j < 4; ++j) {
          bf16x8 bk = *(const bf16x8*)(Ks + (((j * 16 + lm) * 16 + (kc ^ rx)) * 8));
          sc[j] = MFMA32(aqB[ks], bk, sc[j]);
        }
      }
      __builtin_amdgcn_s_setprio(0);
      const bool diag = (kt == qtB);
#pragma unroll
      for (int r = 0; r < 4; ++r) {
        const int qcol = wrow + quad * 4 + r;
        const int prow = (wrow + quad * 4 + r) * 72;
#pragma unroll
        for (int j = 0; j < 4; ++j) {
          float p = __builtin_amdgcn_exp2f(fminf(sc[j][r], 30.0f));
          if (diag && (j * 16 + lm > qcol)) p = 0.f;
          PsB[prow + j * 16 + lm] = f2b(p);
        }
      }

      __builtin_amdgcn_s_setprio(1);
#pragma unroll
      for (int ks = 0; ks < 2; ++ks) {
        bf16x8 ap = *(const bf16x8*)(PsB + (wrow + lm) * 72 + ks * 32 + quad * 8);
        const int kc = ks * 4 + quad;
        lsumB = MFMA32(ap, vones, lsumB);
#pragma unroll
        for (int t = 0; t < 8; ++t) {
          bf16x8 bv = *(const bf16x8*)(Vs + (((t * 16 + lm) * 8 + (kc ^ rx)) * 8));
          oaccB[t] = MFMA32(ap, bv, oaccB[t]);
        }
      }
      __builtin_amdgcn_s_setprio(0);
    }
  }

  // epilogues
#pragma unroll
  for (int r = 0; r < 4; ++r) {
    const int rr = quad * 4 + r;
    {
      float inv = 1.0f / lsumA[r];
      const int srow = qtA * 64 + wrow + rr;
      u16* Orow = O + ((size_t)b * S + srow) * 2048 + h * 128;
#pragma unroll
      for (int t = 0; t < 8; ++t) Orow[t * 16 + lm] = f2b(oaccA[t][r] * inv);
    }
    {
      float inv = 1.0f / lsumB[r];
      const int srow = qtB * 64 + wrow + rr;
      u16* Orow = O + ((size_t)b * S + srow) * 2048 + h * 128;
#pragma unroll
      for (int t = 0; t < 8; ++t) Orow[t * 16 + lm] = f2b(oaccB[t][r] * inv);
    }
  }
}

extern "C" void kernel_launch(void* const* d_in, const int* in_sizes, int n_in,
                              void* d_out, int out_size, void* d_ws, size_t ws_size,
                              hipStream_t stream) {
  const float* x      = (const float*)d_in[0];
  const float* Wq_sem = (const float*)d_in[1];
  const float* Wk_sem = (const float*)d_in[2];
  const float* Wq_geo = (const float*)d_in[3];
  const float* Wk_geo = (const float*)d_in[4];
  const float* Wv     = (const float*)d_in[5];
  const float* Wo     = (const float*)d_in[6];

  char* ws = (char*)d_ws;
  // layout (bytes):
  //   [0, 16M)          xb  (x bf16, 4096x2048)
  //   [16M, 41.2M)      Wall (6144x2048 bf16)   -> later reused as O
  //   [41.2M, 49.6M)    Wob  (2048x2048 bf16)
  //   [49.6M, 66.3M)    Qb   (bf16, 32 heads x 2048 x 128)
  // d_out (33.5MB) used as scratch for K (16.7M) + VT (16.7M) until final GEMM.
  u16* xb   = (u16*)(ws);
  u16* Wall = (u16*)(ws + 16777216);
  u16* Wob  = (u16*)(ws + 16777216 + 25165824);
  u16* Qb   = (u16*)(ws + 16777216 + 25165824 + 8388608);
  u16* Ob   = Wall;
  u16* Kb   = (u16*)d_out;
  u16* VT   = (u16*)((char*)d_out + 16777216);

  // all casts in one launch
  cast_all<<<24576, 256, 0, stream>>>(x, Wq_sem, Wk_sem, Wq_geo, Wk_geo, Wv, Wo,
                                      xb, Wall, Wob);

  // fused QKV projection + RoPE + head rearrange: writes Q/K/VT directly
  gemm_qkv<<<dim3(48, 32), 256, 0, stream>>>(xb, Wall, Qb, Kb, VT);

  // causal flash attention -> O (B*S, 2048) bf16
  attn_v11<<<dim3(16, 32), 256, 0, stream>>>(Qb, Kb, VT, Ob);

  // final projection: out = O @ Wo^T  (M=4096, N=2048, K=2048), fp32 out
  gemm_bt<false><<<dim3(16, 32), 256, 0, stream>>>(Ob, Wob, d_out, 2048, 2048);
}

// Round 13
// 376.185 us; speedup vs baseline: 1.3646x; 1.3646x over previous
//
#include <hip/hip_runtime.h>
#include <cstdint>
#include <cstddef>

typedef unsigned short u16;
typedef __attribute__((ext_vector_type(8))) short bf16x8;
typedef __attribute__((ext_vector_type(4))) float f32x4;

#define MFMA32(a, b, c) __builtin_amdgcn_mfma_f32_16x16x32_bf16(a, b, c, 0, 0, 0)

__device__ __forceinline__ u16 f2b(float f) {
  union { float f; unsigned u; } v; v.f = f;
  unsigned u = v.u;
  return (u16)((u + 0x7fffu + ((u >> 16) & 1u)) >> 16);
}
__device__ __forceinline__ float b2f(u16 h) {
  union { unsigned u; float f; } v; v.u = ((unsigned)h) << 16;
  return v.f;
}

// async global->LDS, 16B per lane. LDS dest must be wave-uniform base + lane*16.
__device__ __forceinline__ void g2l16(const void* g, void* l) {
  __builtin_amdgcn_global_load_lds((__attribute__((address_space(1))) void*)(g),
                                   (__attribute__((address_space(3))) void*)(l), 16, 0, 0);
}

// ---------------- ALL fp32->bf16 casts in one launch --------------------------
__global__ __launch_bounds__(256) void cast_all(const float* __restrict__ x,
                                                const float* __restrict__ W0,
                                                const float* __restrict__ W1,
                                                const float* __restrict__ W2,
                                                const float* __restrict__ W3,
                                                const float* __restrict__ Wv,
                                                const float* __restrict__ Wo,
                                                u16* __restrict__ xb,
                                                u16* __restrict__ Wall,
                                                u16* __restrict__ Wob) {
  const int blk = blockIdx.x;
  const float* src;
  u16* dst;
  int li;
  if (blk < 8192) {
    src = x; dst = xb; li = blk * 256 + threadIdx.x;
  } else if (blk < 16384) {
    const int s = (blk - 8192) >> 11;
    src = s == 0 ? W0 : s == 1 ? W1 : s == 2 ? W2 : W3;
    dst = Wall + (size_t)s * 2097152;
    li = ((blk - 8192) & 2047) * 256 + threadIdx.x;
  } else if (blk < 20480) {
    src = Wv; dst = Wall + (size_t)4 * 2097152;
    li = (blk - 16384) * 256 + threadIdx.x;
  } else {
    src = Wo; dst = Wob;
    li = (blk - 20480) * 256 + threadIdx.x;
  }
  float4 v = ((const float4*)src)[li];
  ushort4 r;
  r.x = f2b(v.x); r.y = f2b(v.y); r.z = f2b(v.z); r.w = f2b(v.w);
  ((ushort4*)dst)[li] = r;
}

// ---------------- C = A @ B^T  128x128 tile (m97 structure; final projection) -
template <bool BF16_OUT>
__global__ __launch_bounds__(256) void gemm_bt(const u16* __restrict__ A,
                                               const u16* __restrict__ B,
                                               void* __restrict__ C, int N, int K) {
  __shared__ u16 As[128 * 64];
  __shared__ u16 Bs[128 * 64];
  const int tid = threadIdx.x;
  const int wid = tid >> 6;
  const int lane = tid & 63;
  const int lm = lane & 15;
  const int quad = lane >> 4;
  const int r3 = lm & 7;
  const int wm = (wid & 1) * 64;
  const int wn = (wid >> 1) * 64;
  const int bm = blockIdx.y * 128;
  const int bn = blockIdx.x * 128;

  const u16* Ab = A + (size_t)bm * K;
  const u16* Bb = B + (size_t)bn * K;

  f32x4 zero = {0.f, 0.f, 0.f, 0.f};
  f32x4 acc[4][4];
#pragma unroll
  for (int i = 0; i < 4; ++i)
#pragma unroll
    for (int j = 0; j < 4; ++j) acc[i][j] = zero;

  for (int k0 = 0; k0 < K; k0 += 64) {
#pragma unroll
    for (int it = 0; it < 4; ++it) {
      int c = it * 256 + tid;
      int rg = c >> 6, rw = (c >> 3) & 7, u = c & 7;
      int row = rg * 8 + rw;
      int chd = u ^ rw;
      g2l16(Ab + (size_t)row * K + k0 + chd * 8, As + c * 8);
      g2l16(Bb + (size_t)row * K + k0 + chd * 8, Bs + c * 8);
    }
    __syncthreads();
#pragma unroll
    for (int ks = 0; ks < 2; ++ks) {
      bf16x8 a[4], b[4];
      int chd = ks * 4 + quad;
#pragma unroll
      for (int i = 0; i < 4; ++i) {
        int row = wm + i * 16 + lm;
        a[i] = *(const bf16x8*)(As + (((row >> 3) * 64 + r3 * 8 + (chd ^ r3)) * 8));
      }
#pragma unroll
      for (int j = 0; j < 4; ++j) {
        int row = wn + j * 16 + lm;
        b[j] = *(const bf16x8*)(Bs + (((row >> 3) * 64 + r3 * 8 + (chd ^ r3)) * 8));
      }
#pragma unroll
      for (int i = 0; i < 4; ++i)
#pragma unroll
        for (int j = 0; j < 4; ++j)
          acc[i][j] = MFMA32(a[i], b[j], acc[i][j]);
    }
    __syncthreads();
  }

#pragma unroll
  for (int i = 0; i < 4; ++i)
#pragma unroll
    for (int j = 0; j < 4; ++j)
#pragma unroll
      for (int r = 0; r < 4; ++r) {
        int row = bm + wm + i * 16 + quad * 4 + r;
        int col = bn + wn + j * 16 + lm;
        float v = acc[i][j][r];
        if (BF16_OUT)
          ((u16*)C)[(size_t)row * N + col] = f2b(v);
        else
          ((float*)C)[(size_t)row * N + col] = v;
      }
}

// ---------------- QKV GEMM with fused RoPE/rearrange epilogue v3 (hybrid) -----
__global__ __launch_bounds__(256) void gemm_qkv(const u16* __restrict__ A,
                                                const u16* __restrict__ B,
                                                u16* __restrict__ Qb,
                                                u16* __restrict__ Kb,
                                                u16* __restrict__ VT) {
  constexpr int K = 2048;
  const float SC = 0.12751744f;  // (1/sqrt(128)) * log2(e)
  __shared__ u16 sh[16384];      // As | Bs, reused for V staging
  u16* As = sh;
  u16* Bs = sh + 8192;
  const int tid = threadIdx.x;
  const int wid = tid >> 6;
  const int lane = tid & 63;
  const int lm = lane & 15;
  const int quad = lane >> 4;
  const int r3 = lm & 7;
  const int wm = (wid & 1) * 64;
  const int wn = (wid >> 1) * 64;
  const int bm = blockIdx.y * 128;
  const int bn = blockIdx.x * 128;

  const u16* Ab = A + (size_t)bm * K;
  const u16* Bb = B + (size_t)bn * K;

  f32x4 zero = {0.f, 0.f, 0.f, 0.f};
  f32x4 acc[4][4];
#pragma unroll
  for (int i = 0; i < 4; ++i)
#pragma unroll
    for (int j = 0; j < 4; ++j) acc[i][j] = zero;

  for (int k0 = 0; k0 < K; k0 += 64) {
#pragma unroll
    for (int it = 0; it < 4; ++it) {
      int c = it * 256 + tid;
      int rg = c >> 6, rw = (c >> 3) & 7, u = c & 7;
      int row = rg * 8 + rw;
      int chd = u ^ rw;
      g2l16(Ab + (size_t)row * K + k0 + chd * 8, As + c * 8);
      g2l16(Bb + (size_t)row * K + k0 + chd * 8, Bs + c * 8);
    }
    __syncthreads();
#pragma unroll
    for (int ks = 0; ks < 2; ++ks) {
      bf16x8 a[4], b[4];
      int chd = ks * 4 + quad;
#pragma unroll
      for (int i = 0; i < 4; ++i) {
        int row = wm + i * 16 + lm;
        a[i] = *(const bf16x8*)(As + (((row >> 3) * 64 + r3 * 8 + (chd ^ r3)) * 8));
      }
#pragma unroll
      for (int j = 0; j < 4; ++j) {
        int row = wn + j * 16 + lm;
        b[j] = *(const bf16x8*)(Bs + (((row >> 3) * 64 + r3 * 8 + (chd ^ r3)) * 8));
      }
#pragma unroll
      for (int i = 0; i < 4; ++i)
#pragma unroll
        for (int j = 0; j < 4; ++j)
          acc[i][j] = MFMA32(a[i], b[j], acc[i][j]);
    }
    __syncthreads();
  }

  const int seg = bn >> 10;       // uniform per block
  const int b = bm >> 11;
  const int sbase = bm & 2047;
  const int h = ((bn + wn) >> 6) & 15;  // head for Q/K segments
  const size_t bhQ = (size_t)b * 16 + h;

  if (seg < 2) {
    // ---- sem: direct copy ----
    u16* dst = (seg == 0) ? Qb : Kb;
    const float sc = (seg == 0) ? SC : 1.0f;
#pragma unroll
    for (int i = 0; i < 4; ++i)
#pragma unroll
      for (int r = 0; r < 4; ++r) {
        const int s = sbase + wm + i * 16 + quad * 4 + r;
        u16* base = dst + (bhQ * 2048 + s) * 128;
#pragma unroll
        for (int j = 0; j < 4; ++j) {
          const int d = (wn + j * 16 + lm) & 63;
          base[d] = f2b(acc[i][j][r] * sc);
        }
      }
  } else if (seg < 4) {
    // ---- geo: RoPE in-register, write d in [64,128) ----
    u16* dst = (seg == 2) ? Qb : Kb;
    const float sc = (seg == 2) ? SC : 1.0f;
    const float inv0 = __powf(10000.0f, -(float)(2 * lm) * (1.0f / 64.0f));
    const float inv1 = __powf(10000.0f, -(float)(2 * (16 + lm)) * (1.0f / 64.0f));
#pragma unroll
    for (int i = 0; i < 4; ++i)
#pragma unroll
      for (int r = 0; r < 4; ++r) {
        const int s = sbase + wm + i * 16 + quad * 4 + r;
        float sn0, cs0, sn1, cs1;
        __sincosf((float)s * inv0, &sn0, &cs0);
        __sincosf((float)s * inv1, &sn1, &cs1);
        const float x1a = acc[i][0][r], x2a = acc[i][2][r];  // f0 = lm
        const float x1b = acc[i][1][r], x2b = acc[i][3][r];  // f0 = 16+lm
        u16* base = dst + (bhQ * 2048 + s) * 128 + 64;
        base[lm]      = f2b((x1a * cs0 - x2a * sn0) * sc);
        base[16 + lm] = f2b((x1b * cs1 - x2b * sn1) * sc);
        base[32 + lm] = f2b((x1a * sn0 + x2a * cs0) * sc);
        base[48 + lm] = f2b((x1b * sn1 + x2b * cs1) * sc);
      }
  } else {
    // ---- V: stage TRANSPOSED [d][s] swizzled, write coalesced VT rows -------
    const int hv = (bn - 4096) >> 7;   // one head per tile
    const size_t bh = (size_t)b * 16 + hv;
#pragma unroll
    for (int i = 0; i < 4; ++i)
#pragma unroll
      for (int r = 0; r < 4; ++r) {
        const int sr = wm + i * 16 + quad * 4 + r;
#pragma unroll
        for (int j = 0; j < 4; ++j) {
          const int d = wn + j * 16 + lm;
          sh[d * 128 + (((sr >> 3) ^ (d & 7)) << 3) + (sr & 7)] = f2b(acc[i][j][r]);
        }
      }
    __syncthreads();
#pragma unroll
    for (int it = 0; it < 8; ++it) {
      const int idx = it * 256 + tid;
      const int d = idx >> 4;      // 0..127
      const int ch = idx & 15;     // 8-s chunk
      bf16x8 v = *(const bf16x8*)(sh + d * 128 + ((ch ^ (d & 7)) << 3));
      *(bf16x8*)(VT + (bh * 128 + d) * 2048 + sbase + ch * 8) = v;
    }
  }
}

// ---------------- fused causal attention v12: shared-fragment dual-q, 2 blk/CU
// v11's fusion arithmetic was right (LDS-read traffic halves in the dual
// region) but launch_bounds(256,3) capped VGPR at ~85 -> massive scratch
// spill (WRITE_SIZE 16MB -> 509MB). v12 = v11 with launch_bounds(256,2):
// VGPR cap ~256 fits the ~190-reg working set; 8 waves/CU still saturate the
// LDS pipe (kernel is LDS-BANDWIDTH bound, not latency bound; v8 ran 2/CU).
__global__ __launch_bounds__(256, 2) void attn_v12(const u16* __restrict__ Q,
                                                   const u16* __restrict__ K,
                                                   const u16* __restrict__ VT,
                                                   u16* __restrict__ O) {
  constexpr int S = 2048;
  constexpr int D = 128;
  __shared__ u16 Ks[64 * 128];   // chunk-swizzled
  __shared__ u16 Vs[128 * 64];   // VT tile [d][s_local], chunk-swizzled
  __shared__ u16 PsA[64 * 72];   // wave-private rows; padded stride 72
  __shared__ u16 PsB[64 * 72];
  const int linear = blockIdx.x + (blockIdx.y << 4);
  const int xcd = linear & 7;
  const int slot = linear >> 3;          // 0..63
  const int bh = (xcd << 2) + (slot >> 4);
  const int bx = slot & 15;
  const int b = bh >> 4, h = bh & 15;
  const int tid = threadIdx.x, wid = tid >> 6, lane = tid & 63;
  const int lm = lane & 15, quad = lane >> 4;
  const int rx = lm & 7;
  const int wrow = wid * 16;

  const int qtA = bx;        // 0..15
  const int qtB = 31 - bx;   // 16..31 (always > qtA)

  const u16* Kbh = K + (size_t)bh * S * D;
  const u16* Vbh = VT + (size_t)bh * D * S;

  const bf16x8 vones = {16256, 16256, 16256, 16256, 16256, 16256, 16256, 16256};  // bf16 1.0

  bf16x8 aqA[4], aqB[4];
#pragma unroll
  for (int ks = 0; ks < 4; ++ks) {
    aqA[ks] = *(const bf16x8*)(Q + ((size_t)bh * S + (size_t)qtA * 64 + wrow + lm) * D +
                               ks * 32 + quad * 8);
    aqB[ks] = *(const bf16x8*)(Q + ((size_t)bh * S + (size_t)qtB * 64 + wrow + lm) * D +
                               ks * 32 + quad * 8);
  }

  f32x4 zero = {0.f, 0.f, 0.f, 0.f};
  f32x4 lsumA = zero, lsumB = zero;
  f32x4 oaccA[8], oaccB[8];
#pragma unroll
  for (int t = 0; t < 8; ++t) { oaccA[t] = zero; oaccB[t] = zero; }

#pragma unroll 1
  for (int kt = 0; kt <= qtB; ++kt) {
    __syncthreads();  // prior iteration's readers done with Ks/Vs
    const u16* Kt = Kbh + (size_t)kt * 64 * D;
    const u16* Vt = Vbh + (size_t)kt * 64;
#pragma unroll
    for (int it = 0; it < 4; ++it) {
      int c = it * 256 + tid;
      int row = c >> 4, u = c & 15;
      g2l16(Kt + (size_t)row * 128 + (size_t)(u ^ (row & 7)) * 8, Ks + c * 8);
    }
#pragma unroll
    for (int it = 0; it < 4; ++it) {
      int c = it * 256 + tid;
      int row = c >> 3, u = c & 7;
      g2l16(Vt + (size_t)row * S + (size_t)(u ^ (row & 7)) * 8, Vs + c * 8);
    }
    __syncthreads();  // barrier drains vmcnt: staged data visible

    if (kt <= qtA) {
      // ======== dual region: each fragment read feeds TWO MFMAs ========
      f32x4 scA[4], scB[4];
#pragma unroll
      for (int j = 0; j < 4; ++j) { scA[j] = zero; scB[j] = zero; }
      __builtin_amdgcn_s_setprio(1);
#pragma unroll
      for (int ks = 0; ks < 4; ++ks) {
        const int kc = ks * 4 + quad;
#pragma unroll
        for (int j = 0; j < 4; ++j) {
          bf16x8 bk = *(const bf16x8*)(Ks + (((j * 16 + lm) * 16 + (kc ^ rx)) * 8));
          scB[j] = MFMA32(aqB[ks], bk, scB[j]);
          scA[j] = MFMA32(aqA[ks], bk, scA[j]);
        }
      }
      __builtin_amdgcn_s_setprio(0);

      const bool diagA = (kt == qtA);
#pragma unroll
      for (int r = 0; r < 4; ++r) {
        const int qcol = wrow + quad * 4 + r;
        const int prow = (wrow + quad * 4 + r) * 72;
#pragma unroll
        for (int j = 0; j < 4; ++j) {
          float pB = __builtin_amdgcn_exp2f(fminf(scB[j][r], 30.0f));
          float pA = __builtin_amdgcn_exp2f(fminf(scA[j][r], 30.0f));
          if (diagA && (j * 16 + lm > qcol)) pA = 0.f;  // diag B impossible here (kt<=qtA<qtB)
          PsB[prow + j * 16 + lm] = f2b(pB);
          PsA[prow + j * 16 + lm] = f2b(pA);
        }
      }
      // no barrier: Ps rows are wave-private (proven R4)

      __builtin_amdgcn_s_setprio(1);
#pragma unroll
      for (int ks = 0; ks < 2; ++ks) {
        bf16x8 apB = *(const bf16x8*)(PsB + (wrow + lm) * 72 + ks * 32 + quad * 8);
        bf16x8 apA = *(const bf16x8*)(PsA + (wrow + lm) * 72 + ks * 32 + quad * 8);
        const int kc = ks * 4 + quad;
        lsumB = MFMA32(apB, vones, lsumB);
        lsumA = MFMA32(apA, vones, lsumA);
#pragma unroll
        for (int t = 0; t < 8; ++t) {
          bf16x8 bv = *(const bf16x8*)(Vs + (((t * 16 + lm) * 8 + (kc ^ rx)) * 8));
          oaccB[t] = MFMA32(apB, bv, oaccB[t]);
          oaccA[t] = MFMA32(apA, bv, oaccA[t]);
        }
      }
      __builtin_amdgcn_s_setprio(0);
    } else {
      // ======== B-only region (kt > qtA) ========
      f32x4 sc[4];
#pragma unroll
      for (int j = 0; j < 4; ++j) sc[j] = zero;
      __builtin_amdgcn_s_setprio(1);
#pragma unroll
      for (int ks = 0; ks < 4; ++ks) {
        const int kc = ks * 4 + quad;
#pragma unroll
        for (int j = 0; j < 4; ++j) {
          bf16x8 bk = *(const bf16x8*)(Ks + (((j * 16 + lm) * 16 + (kc ^ rx)) * 8));
          sc[j] = MFMA32(aqB[ks], bk, sc[j]);
        }
      }
      __builtin_amdgcn_s_setprio(0);
      const bool diag = (kt == qtB);
#pragma unroll
      for (int r = 0; r < 4; ++r) {
        const int qcol = wrow + quad * 4 + r;
        const int prow = (wrow + quad * 4 + r) * 72;
#pragma unroll
        for (int j = 0; j < 4; ++j) {
          float p = __builtin_amdgcn_exp2f(fminf(sc[j][r], 30.0f));
          if (diag && (j * 16 + lm > qcol)) p = 0.f;
          PsB[prow + j * 16 + lm] = f2b(p);
        }
      }

      __builtin_amdgcn_s_setprio(1);
#pragma unroll
      for (int ks = 0; ks < 2; ++ks) {
        bf16x8 ap = *(const bf16x8*)(PsB + (wrow + lm) * 72 + ks * 32 + quad * 8);
        const int kc = ks * 4 + quad;
        lsumB = MFMA32(ap, vones, lsumB);
#pragma unroll
        for (int t = 0; t < 8; ++t) {
          bf16x8 bv = *(const bf16x8*)(Vs + (((t * 16 + lm) * 8 + (kc ^ rx)) * 8));
          oaccB[t] = MFMA32(ap, bv, oaccB[t]);
        }
      }
      __builtin_amdgcn_s_setprio(0);
    }
  }

  // epilogues
#pragma unroll
  for (int r = 0; r < 4; ++r) {
    const int rr = quad * 4 + r;
    {
      float inv = 1.0f / lsumA[r];
      const int srow = qtA * 64 + wrow + rr;
      u16* Orow = O + ((size_t)b * S + srow) * 2048 + h * 128;
#pragma unroll
      for (int t = 0; t < 8; ++t) Orow[t * 16 + lm] = f2b(oaccA[t][r] * inv);
    }
    {
      float inv = 1.0f / lsumB[r];
      const int srow = qtB * 64 + wrow + rr;
      u16* Orow = O + ((size_t)b * S + srow) * 2048 + h * 128;
#pragma unroll
      for (int t = 0; t < 8; ++t) Orow[t * 16 + lm] = f2b(oaccB[t][r] * inv);
    }
  }
}

extern "C" void kernel_launch(void* const* d_in, const int* in_sizes, int n_in,
                              void* d_out, int out_size, void* d_ws, size_t ws_size,
                              hipStream_t stream) {
  const float* x      = (const float*)d_in[0];
  const float* Wq_sem = (const float*)d_in[1];
  const float* Wk_sem = (const float*)d_in[2];
  const float* Wq_geo = (const float*)d_in[3];
  const float* Wk_geo = (const float*)d_in[4];
  const float* Wv     = (const float*)d_in[5];
  const float* Wo     = (const float*)d_in[6];

  char* ws = (char*)d_ws;
  // layout (bytes):
  //   [0, 16M)          xb  (x bf16, 4096x2048)
  //   [16M, 41.2M)      Wall (6144x2048 bf16)   -> later reused as O
  //   [41.2M, 49.6M)    Wob  (2048x2048 bf16)
  //   [49.6M, 66.3M)    Qb   (bf16, 32 heads x 2048 x 128)
  // d_out (33.5MB) used as scratch for K (16.7M) + VT (16.7M) until final GEMM.
  u16* xb   = (u16*)(ws);
  u16* Wall = (u16*)(ws + 16777216);
  u16* Wob  = (u16*)(ws + 16777216 + 25165824);
  u16* Qb   = (u16*)(ws + 16777216 + 25165824 + 8388608);
  u16* Ob   = Wall;
  u16* Kb   = (u16*)d_out;
  u16* VT   = (u16*)((char*)d_out + 16777216);

  // all casts in one launch
  cast_all<<<24576, 256, 0, stream>>>(x, Wq_sem, Wk_sem, Wq_geo, Wk_geo, Wv, Wo,
                                      xb, Wall, Wob);

  // fused QKV projection + RoPE + head rearrange: writes Q/K/VT directly
  gemm_qkv<<<dim3(48, 32), 256, 0, stream>>>(xb, Wall, Qb, Kb, VT);

  // causal flash attention -> O (B*S, 2048) bf16
  attn_v12<<<dim3(16, 32), 256, 0, stream>>>(Qb, Kb, VT, Ob);

  // final projection: out = O @ Wo^T  (M=4096, N=2048, K=2048), fp32 out
  gemm_bt<false><<<dim3(16, 32), 256, 0, stream>>>(Ob, Wob, d_out, 2048, 2048);
}

// Round 14
// 362.170 us; speedup vs baseline: 1.4174x; 1.0387x over previous
//
#include <hip/hip_runtime.h>
#include <cstdint>
#include <cstddef>

typedef unsigned short u16;
typedef __attribute__((ext_vector_type(8))) short bf16x8;
typedef __attribute__((ext_vector_type(4))) float f32x4;

#define MFMA32(a, b, c) __builtin_amdgcn_mfma_f32_16x16x32_bf16(a, b, c, 0, 0, 0)

__device__ __forceinline__ u16 f2b(float f) {
  union { float f; unsigned u; } v; v.f = f;
  unsigned u = v.u;
  return (u16)((u + 0x7fffu + ((u >> 16) & 1u)) >> 16);
}
__device__ __forceinline__ float b2f(u16 h) {
  union { unsigned u; float f; } v; v.u = ((unsigned)h) << 16;
  return v.f;
}

// async global->LDS, 16B per lane. LDS dest must be wave-uniform base + lane*16.
__device__ __forceinline__ void g2l16(const void* g, void* l) {
  __builtin_amdgcn_global_load_lds((__attribute__((address_space(1))) void*)(g),
                                   (__attribute__((address_space(3))) void*)(l), 16, 0, 0);
}

// ---------------- ALL fp32->bf16 casts + RoPE cos/sin table in one launch ----
// blocks 0..8191: x -> xb; 8192..16383: W0..W3 -> Wall[0..3];
// 16384..20479: Wv -> Wall[4]; 20480..24575: Wo -> Wob;
// 24576..24831: rope table tab[s*32+f] = {cos(s*inv_f), sin(s*inv_f)}.
__global__ __launch_bounds__(256) void cast_all(const float* __restrict__ x,
                                                const float* __restrict__ W0,
                                                const float* __restrict__ W1,
                                                const float* __restrict__ W2,
                                                const float* __restrict__ W3,
                                                const float* __restrict__ Wv,
                                                const float* __restrict__ Wo,
                                                u16* __restrict__ xb,
                                                u16* __restrict__ Wall,
                                                u16* __restrict__ Wob,
                                                float2* __restrict__ tab) {
  const int blk = blockIdx.x;
  if (blk >= 24576) {
    const int idx = (blk - 24576) * 256 + threadIdx.x;  // 0..65535
    const int s = idx >> 5, f = idx & 31;
    const float inv = __powf(10000.0f, -(float)(2 * f) * (1.0f / 64.0f));
    const float ang = (float)s * inv;
    tab[idx] = make_float2(cosf(ang), sinf(ang));
    return;
  }
  const float* src;
  u16* dst;
  int li;
  if (blk < 8192) {
    src = x; dst = xb; li = blk * 256 + threadIdx.x;
  } else if (blk < 16384) {
    const int s = (blk - 8192) >> 11;
    src = s == 0 ? W0 : s == 1 ? W1 : s == 2 ? W2 : W3;
    dst = Wall + (size_t)s * 2097152;
    li = ((blk - 8192) & 2047) * 256 + threadIdx.x;
  } else if (blk < 20480) {
    src = Wv; dst = Wall + (size_t)4 * 2097152;
    li = (blk - 16384) * 256 + threadIdx.x;
  } else {
    src = Wo; dst = Wob;
    li = (blk - 20480) * 256 + threadIdx.x;
  }
  float4 v = ((const float4*)src)[li];
  ushort4 r;
  r.x = f2b(v.x); r.y = f2b(v.y); r.z = f2b(v.z); r.w = f2b(v.w);
  ((ushort4*)dst)[li] = r;
}

// ---------------- C = A @ B^T  128x128 tile (m97 structure; final projection) -
template <bool BF16_OUT>
__global__ __launch_bounds__(256) void gemm_bt(const u16* __restrict__ A,
                                               const u16* __restrict__ B,
                                               void* __restrict__ C, int N, int K) {
  __shared__ u16 As[128 * 64];
  __shared__ u16 Bs[128 * 64];
  const int tid = threadIdx.x;
  const int wid = tid >> 6;
  const int lane = tid & 63;
  const int lm = lane & 15;
  const int quad = lane >> 4;
  const int r3 = lm & 7;
  const int wm = (wid & 1) * 64;
  const int wn = (wid >> 1) * 64;
  const int bm = blockIdx.y * 128;
  const int bn = blockIdx.x * 128;

  const u16* Ab = A + (size_t)bm * K;
  const u16* Bb = B + (size_t)bn * K;

  f32x4 zero = {0.f, 0.f, 0.f, 0.f};
  f32x4 acc[4][4];
#pragma unroll
  for (int i = 0; i < 4; ++i)
#pragma unroll
    for (int j = 0; j < 4; ++j) acc[i][j] = zero;

  for (int k0 = 0; k0 < K; k0 += 64) {
#pragma unroll
    for (int it = 0; it < 4; ++it) {
      int c = it * 256 + tid;
      int rg = c >> 6, rw = (c >> 3) & 7, u = c & 7;
      int row = rg * 8 + rw;
      int chd = u ^ rw;
      g2l16(Ab + (size_t)row * K + k0 + chd * 8, As + c * 8);
      g2l16(Bb + (size_t)row * K + k0 + chd * 8, Bs + c * 8);
    }
    __syncthreads();
#pragma unroll
    for (int ks = 0; ks < 2; ++ks) {
      bf16x8 a[4], b[4];
      int chd = ks * 4 + quad;
#pragma unroll
      for (int i = 0; i < 4; ++i) {
        int row = wm + i * 16 + lm;
        a[i] = *(const bf16x8*)(As + (((row >> 3) * 64 + r3 * 8 + (chd ^ r3)) * 8));
      }
#pragma unroll
      for (int j = 0; j < 4; ++j) {
        int row = wn + j * 16 + lm;
        b[j] = *(const bf16x8*)(Bs + (((row >> 3) * 64 + r3 * 8 + (chd ^ r3)) * 8));
      }
#pragma unroll
      for (int i = 0; i < 4; ++i)
#pragma unroll
        for (int j = 0; j < 4; ++j)
          acc[i][j] = MFMA32(a[i], b[j], acc[i][j]);
    }
    __syncthreads();
  }

#pragma unroll
  for (int i = 0; i < 4; ++i)
#pragma unroll
    for (int j = 0; j < 4; ++j)
#pragma unroll
      for (int r = 0; r < 4; ++r) {
        int row = bm + wm + i * 16 + quad * 4 + r;
        int col = bn + wn + j * 16 + lm;
        float v = acc[i][j][r];
        if (BF16_OUT)
          ((u16*)C)[(size_t)row * N + col] = f2b(v);
        else
          ((float*)C)[(size_t)row * N + col] = v;
      }
}

// ---------------- QKV GEMM with fused RoPE/rearrange epilogue v4 --------------
// v3 hybrid (R10-proven) + geo sincos replaced by table lookups: the geo path
// computed 32 __sincosf + 2 __powf per thread (~1000 VALU cycles); now 2x 8B
// coalesced L2-resident loads per (i,r).
__global__ __launch_bounds__(256) void gemm_qkv(const u16* __restrict__ A,
                                                const u16* __restrict__ B,
                                                u16* __restrict__ Qb,
                                                u16* __restrict__ Kb,
                                                u16* __restrict__ VT,
                                                const float2* __restrict__ tab) {
  constexpr int K = 2048;
  const float SC = 0.12751744f;  // (1/sqrt(128)) * log2(e)
  __shared__ u16 sh[16384];      // As | Bs, reused for V staging
  u16* As = sh;
  u16* Bs = sh + 8192;
  const int tid = threadIdx.x;
  const int wid = tid >> 6;
  const int lane = tid & 63;
  const int lm = lane & 15;
  const int quad = lane >> 4;
  const int r3 = lm & 7;
  const int wm = (wid & 1) * 64;
  const int wn = (wid >> 1) * 64;
  const int bm = blockIdx.y * 128;
  const int bn = blockIdx.x * 128;

  const u16* Ab = A + (size_t)bm * K;
  const u16* Bb = B + (size_t)bn * K;

  f32x4 zero = {0.f, 0.f, 0.f, 0.f};
  f32x4 acc[4][4];
#pragma unroll
  for (int i = 0; i < 4; ++i)
#pragma unroll
    for (int j = 0; j < 4; ++j) acc[i][j] = zero;

  for (int k0 = 0; k0 < K; k0 += 64) {
#pragma unroll
    for (int it = 0; it < 4; ++it) {
      int c = it * 256 + tid;
      int rg = c >> 6, rw = (c >> 3) & 7, u = c & 7;
      int row = rg * 8 + rw;
      int chd = u ^ rw;
      g2l16(Ab + (size_t)row * K + k0 + chd * 8, As + c * 8);
      g2l16(Bb + (size_t)row * K + k0 + chd * 8, Bs + c * 8);
    }
    __syncthreads();
#pragma unroll
    for (int ks = 0; ks < 2; ++ks) {
      bf16x8 a[4], b[4];
      int chd = ks * 4 + quad;
#pragma unroll
      for (int i = 0; i < 4; ++i) {
        int row = wm + i * 16 + lm;
        a[i] = *(const bf16x8*)(As + (((row >> 3) * 64 + r3 * 8 + (chd ^ r3)) * 8));
      }
#pragma unroll
      for (int j = 0; j < 4; ++j) {
        int row = wn + j * 16 + lm;
        b[j] = *(const bf16x8*)(Bs + (((row >> 3) * 64 + r3 * 8 + (chd ^ r3)) * 8));
      }
#pragma unroll
      for (int i = 0; i < 4; ++i)
#pragma unroll
        for (int j = 0; j < 4; ++j)
          acc[i][j] = MFMA32(a[i], b[j], acc[i][j]);
    }
    __syncthreads();
  }

  const int seg = bn >> 10;       // uniform per block
  const int b = bm >> 11;
  const int sbase = bm & 2047;
  const int h = ((bn + wn) >> 6) & 15;  // head for Q/K segments
  const size_t bhQ = (size_t)b * 16 + h;

  if (seg < 2) {
    // ---- sem: direct copy ----
    u16* dst = (seg == 0) ? Qb : Kb;
    const float sc = (seg == 0) ? SC : 1.0f;
#pragma unroll
    for (int i = 0; i < 4; ++i)
#pragma unroll
      for (int r = 0; r < 4; ++r) {
        const int s = sbase + wm + i * 16 + quad * 4 + r;
        u16* base = dst + (bhQ * 2048 + s) * 128;
#pragma unroll
        for (int j = 0; j < 4; ++j) {
          const int d = (wn + j * 16 + lm) & 63;
          base[d] = f2b(acc[i][j][r] * sc);
        }
      }
  } else if (seg < 4) {
    // ---- geo: RoPE in-register via table, write d in [64,128) ----
    u16* dst = (seg == 2) ? Qb : Kb;
    const float sc = (seg == 2) ? SC : 1.0f;
#pragma unroll
    for (int i = 0; i < 4; ++i)
#pragma unroll
      for (int r = 0; r < 4; ++r) {
        const int s = sbase + wm + i * 16 + quad * 4 + r;
        const float2 t0 = tab[(size_t)s * 32 + lm];        // f0 = lm
        const float2 t1 = tab[(size_t)s * 32 + 16 + lm];   // f0 = 16+lm
        const float cs0 = t0.x, sn0 = t0.y, cs1 = t1.x, sn1 = t1.y;
        const float x1a = acc[i][0][r], x2a = acc[i][2][r];
        const float x1b = acc[i][1][r], x2b = acc[i][3][r];
        u16* base = dst + (bhQ * 2048 + s) * 128 + 64;
        base[lm]      = f2b((x1a * cs0 - x2a * sn0) * sc);
        base[16 + lm] = f2b((x1b * cs1 - x2b * sn1) * sc);
        base[32 + lm] = f2b((x1a * sn0 + x2a * cs0) * sc);
        base[48 + lm] = f2b((x1b * sn1 + x2b * cs1) * sc);
      }
  } else {
    // ---- V: stage TRANSPOSED [d][s] swizzled, write coalesced VT rows -------
    const int hv = (bn - 4096) >> 7;   // one head per tile
    const size_t bh = (size_t)b * 16 + hv;
#pragma unroll
    for (int i = 0; i < 4; ++i)
#pragma unroll
      for (int r = 0; r < 4; ++r) {
        const int sr = wm + i * 16 + quad * 4 + r;
#pragma unroll
        for (int j = 0; j < 4; ++j) {
          const int d = wn + j * 16 + lm;
          sh[d * 128 + (((sr >> 3) ^ (d & 7)) << 3) + (sr & 7)] = f2b(acc[i][j][r]);
        }
      }
    __syncthreads();
#pragma unroll
    for (int it = 0; it < 8; ++it) {
      const int idx = it * 256 + tid;
      const int d = idx >> 4;      // 0..127
      const int ch = idx & 15;     // 8-s chunk
      bf16x8 v = *(const bf16x8*)(sh + d * 128 + ((ch ^ (d & 7)) << 3));
      *(bf16x8*)(VT + (bh * 128 + d) * 2048 + sbase + ch * 8) = v;
    }
  }
}

// ---------------- fused causal attention v9 (R10-proven; ACCEPTED final) ------
// v10-v12 arc closed: dual-q fusion loses to occupancy (latency-bound kernel);
// 3 blocks/CU single-buffer + XCD-affinity remap + MFMA row-sum is the best
// verified configuration.
__global__ __launch_bounds__(256, 3) void attn_v9(const u16* __restrict__ Q,
                                                  const u16* __restrict__ K,
                                                  const u16* __restrict__ VT,
                                                  u16* __restrict__ O) {
  constexpr int S = 2048;
  constexpr int D = 128;
  __shared__ u16 Ks[64 * 128];  // chunk-swizzled
  __shared__ u16 Vs[128 * 64];  // VT tile [d][s_local], chunk-swizzled
  __shared__ u16 Ps[64 * 72];   // wave-private rows; padded stride 72
  const int linear = blockIdx.x + (blockIdx.y << 4);
  const int xcd = linear & 7;
  const int slot = linear >> 3;          // 0..63
  const int bh = (xcd << 2) + (slot >> 4);
  const int bx = slot & 15;
  const int b = bh >> 4, h = bh & 15;
  const int tid = threadIdx.x, wid = tid >> 6, lane = tid & 63;
  const int lm = lane & 15, quad = lane >> 4;
  const int rx = lm & 7;
  const int wrow = wid * 16;

  const u16* Kbh = K + (size_t)bh * S * D;
  const u16* Vbh = VT + (size_t)bh * D * S;

  const bf16x8 vones = {16256, 16256, 16256, 16256, 16256, 16256, 16256, 16256};  // bf16 1.0

#pragma unroll 1
  for (int pass = 0; pass < 2; ++pass) {
    const int qt = pass == 0 ? bx : 31 - bx;

    bf16x8 aq[4];
#pragma unroll
    for (int ks = 0; ks < 4; ++ks)
      aq[ks] = *(const bf16x8*)(Q + ((size_t)bh * S + (size_t)qt * 64 + wrow + lm) * D +
                                ks * 32 + quad * 8);

    f32x4 zero = {0.f, 0.f, 0.f, 0.f};
    f32x4 lsum = zero;
    f32x4 oacc[8];
#pragma unroll
    for (int t = 0; t < 8; ++t) oacc[t] = zero;

#pragma unroll 1
    for (int kt = 0; kt <= qt; ++kt) {
      __syncthreads();  // prior iteration's readers done with Ks/Vs
      const u16* Kt = Kbh + (size_t)kt * 64 * D;
      const u16* Vt = Vbh + (size_t)kt * 64;
#pragma unroll
      for (int it = 0; it < 4; ++it) {
        int c = it * 256 + tid;
        int row = c >> 4, u = c & 15;
        g2l16(Kt + (size_t)row * 128 + (size_t)(u ^ (row & 7)) * 8, Ks + c * 8);
      }
#pragma unroll
      for (int it = 0; it < 4; ++it) {
        int c = it * 256 + tid;
        int row = c >> 3, u = c & 7;
        g2l16(Vt + (size_t)row * S + (size_t)(u ^ (row & 7)) * 8, Vs + c * 8);
      }
      __syncthreads();  // barrier drains vmcnt: staged data visible

      // S-tile = Q K^T
      f32x4 sc[4];
#pragma unroll
      for (int j = 0; j < 4; ++j) sc[j] = zero;
      __builtin_amdgcn_s_setprio(1);
#pragma unroll
      for (int ks = 0; ks < 4; ++ks) {
        const int kc = ks * 4 + quad;
#pragma unroll
        for (int j = 0; j < 4; ++j) {
          bf16x8 bk = *(const bf16x8*)(Ks + (((j * 16 + lm) * 16 + (kc ^ rx)) * 8));
          sc[j] = MFMA32(aq[ks], bk, sc[j]);
        }
      }
      __builtin_amdgcn_s_setprio(0);

      const bool diag = (kt == qt);
#pragma unroll
      for (int r = 0; r < 4; ++r) {
        const int qcol = wrow + quad * 4 + r;
        const int prow = (wrow + quad * 4 + r) * 72;
#pragma unroll
        for (int j = 0; j < 4; ++j) {
          float p = __builtin_amdgcn_exp2f(fminf(sc[j][r], 30.0f));
          if (diag && (j * 16 + lm > qcol)) p = 0.f;
          Ps[prow + j * 16 + lm] = f2b(p);
        }
      }
      // no barrier: Ps rows are wave-private (proven R4)

      // O += P @ V ; row-sum += P @ ones
      __builtin_amdgcn_s_setprio(1);
#pragma unroll
      for (int ks = 0; ks < 2; ++ks) {
        bf16x8 ap = *(const bf16x8*)(Ps + (wrow + lm) * 72 + ks * 32 + quad * 8);
        const int kc = ks * 4 + quad;
        lsum = MFMA32(ap, vones, lsum);
#pragma unroll
        for (int t = 0; t < 8; ++t) {
          bf16x8 bv = *(const bf16x8*)(Vs + (((t * 16 + lm) * 8 + (kc ^ rx)) * 8));
          oacc[t] = MFMA32(ap, bv, oacc[t]);
        }
      }
      __builtin_amdgcn_s_setprio(0);
    }

#pragma unroll
    for (int r = 0; r < 4; ++r) {
      float inv = 1.0f / lsum[r];
      const int srow = qt * 64 + wrow + quad * 4 + r;
      u16* Orow = O + ((size_t)b * S + srow) * 2048 + h * 128;
#pragma unroll
      for (int t = 0; t < 8; ++t) Orow[t * 16 + lm] = f2b(oacc[t][r] * inv);
    }
  }
}

extern "C" void kernel_launch(void* const* d_in, const int* in_sizes, int n_in,
                              void* d_out, int out_size, void* d_ws, size_t ws_size,
                              hipStream_t stream) {
  const float* x      = (const float*)d_in[0];
  const float* Wq_sem = (const float*)d_in[1];
  const float* Wk_sem = (const float*)d_in[2];
  const float* Wq_geo = (const float*)d_in[3];
  const float* Wk_geo = (const float*)d_in[4];
  const float* Wv     = (const float*)d_in[5];
  const float* Wo     = (const float*)d_in[6];

  char* ws = (char*)d_ws;
  // layout (bytes):
  //   [0, 16M)          xb  (x bf16, 4096x2048)
  //   [16M, 41.2M)      Wall (6144x2048 bf16)   -> later reused as O
  //   [41.2M, 49.6M)    Wob  (2048x2048 bf16)
  //   [49.6M, 66.3M)    Qb   (bf16, 32 heads x 2048 x 128)
  //   [70M, 70.5M)      rope cos/sin table (2048x32 float2)
  // d_out (33.5MB) used as scratch for K (16.7M) + VT (16.7M) until final GEMM.
  u16* xb   = (u16*)(ws);
  u16* Wall = (u16*)(ws + 16777216);
  u16* Wob  = (u16*)(ws + 16777216 + 25165824);
  u16* Qb   = (u16*)(ws + 16777216 + 25165824 + 8388608);
  float2* tab = (float2*)(ws + 73400320);
  u16* Ob   = Wall;
  u16* Kb   = (u16*)d_out;
  u16* VT   = (u16*)((char*)d_out + 16777216);

  // all casts + rope table in one launch
  cast_all<<<24832, 256, 0, stream>>>(x, Wq_sem, Wk_sem, Wq_geo, Wk_geo, Wv, Wo,
                                      xb, Wall, Wob, tab);

  // fused QKV projection + RoPE + head rearrange: writes Q/K/VT directly
  gemm_qkv<<<dim3(48, 32), 256, 0, stream>>>(xb, Wall, Qb, Kb, VT, tab);

  // causal flash attention -> O (B*S, 2048) bf16
  attn_v9<<<dim3(16, 32), 256, 0, stream>>>(Qb, Kb, VT, Ob);

  // final projection: out = O @ Wo^T  (M=4096, N=2048, K=2048), fp32 out
  gemm_bt<false><<<dim3(16, 32), 256, 0, stream>>>(Ob, Wob, d_out, 2048, 2048);
}

// Round 15
// 361.204 us; speedup vs baseline: 1.4212x; 1.0027x over previous
//
#include <hip/hip_runtime.h>
#include <cstdint>
#include <cstddef>

typedef unsigned short u16;
typedef __attribute__((ext_vector_type(8))) short bf16x8;
typedef __attribute__((ext_vector_type(4))) float f32x4;

#define MFMA32(a, b, c) __builtin_amdgcn_mfma_f32_16x16x32_bf16(a, b, c, 0, 0, 0)

__device__ __forceinline__ u16 f2b(float f) {
  union { float f; unsigned u; } v; v.f = f;
  unsigned u = v.u;
  return (u16)((u + 0x7fffu + ((u >> 16) & 1u)) >> 16);
}
__device__ __forceinline__ float b2f(u16 h) {
  union { unsigned u; float f; } v; v.u = ((unsigned)h) << 16;
  return v.f;
}

// async global->LDS, 16B per lane. LDS dest must be wave-uniform base + lane*16.
__device__ __forceinline__ void g2l16(const void* g, void* l) {
  __builtin_amdgcn_global_load_lds((__attribute__((address_space(1))) void*)(g),
                                   (__attribute__((address_space(3))) void*)(l), 16, 0, 0);
}

// ---------------- ALL fp32->bf16 casts in one launch --------------------------
__global__ __launch_bounds__(256) void cast_all(const float* __restrict__ x,
                                                const float* __restrict__ W0,
                                                const float* __restrict__ W1,
                                                const float* __restrict__ W2,
                                                const float* __restrict__ W3,
                                                const float* __restrict__ Wv,
                                                const float* __restrict__ Wo,
                                                u16* __restrict__ xb,
                                                u16* __restrict__ Wall,
                                                u16* __restrict__ Wob) {
  const int blk = blockIdx.x;
  const float* src;
  u16* dst;
  int li;
  if (blk < 8192) {
    src = x; dst = xb; li = blk * 256 + threadIdx.x;
  } else if (blk < 16384) {
    const int s = (blk - 8192) >> 11;
    src = s == 0 ? W0 : s == 1 ? W1 : s == 2 ? W2 : W3;
    dst = Wall + (size_t)s * 2097152;
    li = ((blk - 8192) & 2047) * 256 + threadIdx.x;
  } else if (blk < 20480) {
    src = Wv; dst = Wall + (size_t)4 * 2097152;
    li = (blk - 16384) * 256 + threadIdx.x;
  } else {
    src = Wo; dst = Wob;
    li = (blk - 20480) * 256 + threadIdx.x;
  }
  float4 v = ((const float4*)src)[li];
  ushort4 r;
  r.x = f2b(v.x); r.y = f2b(v.y); r.z = f2b(v.z); r.w = f2b(v.w);
  ((ushort4*)dst)[li] = r;
}

// ---------------- C = A @ B^T  128x128 tile (m97 structure; final projection) -
template <bool BF16_OUT>
__global__ __launch_bounds__(256) void gemm_bt(const u16* __restrict__ A,
                                               const u16* __restrict__ B,
                                               void* __restrict__ C, int N, int K) {
  __shared__ u16 As[128 * 64];
  __shared__ u16 Bs[128 * 64];
  const int tid = threadIdx.x;
  const int wid = tid >> 6;
  const int lane = tid & 63;
  const int lm = lane & 15;
  const int quad = lane >> 4;
  const int r3 = lm & 7;
  const int wm = (wid & 1) * 64;
  const int wn = (wid >> 1) * 64;
  const int bm = blockIdx.y * 128;
  const int bn = blockIdx.x * 128;

  const u16* Ab = A + (size_t)bm * K;
  const u16* Bb = B + (size_t)bn * K;

  f32x4 zero = {0.f, 0.f, 0.f, 0.f};
  f32x4 acc[4][4];
#pragma unroll
  for (int i = 0; i < 4; ++i)
#pragma unroll
    for (int j = 0; j < 4; ++j) acc[i][j] = zero;

  for (int k0 = 0; k0 < K; k0 += 64) {
#pragma unroll
    for (int it = 0; it < 4; ++it) {
      int c = it * 256 + tid;
      int rg = c >> 6, rw = (c >> 3) & 7, u = c & 7;
      int row = rg * 8 + rw;
      int chd = u ^ rw;
      g2l16(Ab + (size_t)row * K + k0 + chd * 8, As + c * 8);
      g2l16(Bb + (size_t)row * K + k0 + chd * 8, Bs + c * 8);
    }
    __syncthreads();
#pragma unroll
    for (int ks = 0; ks < 2; ++ks) {
      bf16x8 a[4], b[4];
      int chd = ks * 4 + quad;
#pragma unroll
      for (int i = 0; i < 4; ++i) {
        int row = wm + i * 16 + lm;
        a[i] = *(const bf16x8*)(As + (((row >> 3) * 64 + r3 * 8 + (chd ^ r3)) * 8));
      }
#pragma unroll
      for (int j = 0; j < 4; ++j) {
        int row = wn + j * 16 + lm;
        b[j] = *(const bf16x8*)(Bs + (((row >> 3) * 64 + r3 * 8 + (chd ^ r3)) * 8));
      }
#pragma unroll
      for (int i = 0; i < 4; ++i)
#pragma unroll
        for (int j = 0; j < 4; ++j)
          acc[i][j] = MFMA32(a[i], b[j], acc[i][j]);
    }
    __syncthreads();
  }

#pragma unroll
  for (int i = 0; i < 4; ++i)
#pragma unroll
    for (int j = 0; j < 4; ++j)
#pragma unroll
      for (int r = 0; r < 4; ++r) {
        int row = bm + wm + i * 16 + quad * 4 + r;
        int col = bn + wn + j * 16 + lm;
        float v = acc[i][j][r];
        if (BF16_OUT)
          ((u16*)C)[(size_t)row * N + col] = f2b(v);
        else
          ((float*)C)[(size_t)row * N + col] = v;
      }
}

// ---------------- QKV GEMM with fused RoPE/rearrange epilogue v3 (hybrid) -----
// R10-proven best: sem/geo direct scalar stores (cost matches gemm_bt's
// epilogue), V via swizzled LDS staging + coalesced bf16x8 rows. Computed
// sincos (R14's table variant was slightly negative).
__global__ __launch_bounds__(256) void gemm_qkv(const u16* __restrict__ A,
                                                const u16* __restrict__ B,
                                                u16* __restrict__ Qb,
                                                u16* __restrict__ Kb,
                                                u16* __restrict__ VT) {
  constexpr int K = 2048;
  const float SC = 0.12751744f;  // (1/sqrt(128)) * log2(e)
  __shared__ u16 sh[16384];      // As | Bs, reused for V staging
  u16* As = sh;
  u16* Bs = sh + 8192;
  const int tid = threadIdx.x;
  const int wid = tid >> 6;
  const int lane = tid & 63;
  const int lm = lane & 15;
  const int quad = lane >> 4;
  const int r3 = lm & 7;
  const int wm = (wid & 1) * 64;
  const int wn = (wid >> 1) * 64;
  const int bm = blockIdx.y * 128;
  const int bn = blockIdx.x * 128;

  const u16* Ab = A + (size_t)bm * K;
  const u16* Bb = B + (size_t)bn * K;

  f32x4 zero = {0.f, 0.f, 0.f, 0.f};
  f32x4 acc[4][4];
#pragma unroll
  for (int i = 0; i < 4; ++i)
#pragma unroll
    for (int j = 0; j < 4; ++j) acc[i][j] = zero;

  for (int k0 = 0; k0 < K; k0 += 64) {
#pragma unroll
    for (int it = 0; it < 4; ++it) {
      int c = it * 256 + tid;
      int rg = c >> 6, rw = (c >> 3) & 7, u = c & 7;
      int row = rg * 8 + rw;
      int chd = u ^ rw;
      g2l16(Ab + (size_t)row * K + k0 + chd * 8, As + c * 8);
      g2l16(Bb + (size_t)row * K + k0 + chd * 8, Bs + c * 8);
    }
    __syncthreads();
#pragma unroll
    for (int ks = 0; ks < 2; ++ks) {
      bf16x8 a[4], b[4];
      int chd = ks * 4 + quad;
#pragma unroll
      for (int i = 0; i < 4; ++i) {
        int row = wm + i * 16 + lm;
        a[i] = *(const bf16x8*)(As + (((row >> 3) * 64 + r3 * 8 + (chd ^ r3)) * 8));
      }
#pragma unroll
      for (int j = 0; j < 4; ++j) {
        int row = wn + j * 16 + lm;
        b[j] = *(const bf16x8*)(Bs + (((row >> 3) * 64 + r3 * 8 + (chd ^ r3)) * 8));
      }
#pragma unroll
      for (int i = 0; i < 4; ++i)
#pragma unroll
        for (int j = 0; j < 4; ++j)
          acc[i][j] = MFMA32(a[i], b[j], acc[i][j]);
    }
    __syncthreads();
  }

  const int seg = bn >> 10;       // uniform per block
  const int b = bm >> 11;
  const int sbase = bm & 2047;
  const int h = ((bn + wn) >> 6) & 15;  // head for Q/K segments
  const size_t bhQ = (size_t)b * 16 + h;

  if (seg < 2) {
    // ---- sem: direct copy ----
    u16* dst = (seg == 0) ? Qb : Kb;
    const float sc = (seg == 0) ? SC : 1.0f;
#pragma unroll
    for (int i = 0; i < 4; ++i)
#pragma unroll
      for (int r = 0; r < 4; ++r) {
        const int s = sbase + wm + i * 16 + quad * 4 + r;
        u16* base = dst + (bhQ * 2048 + s) * 128;
#pragma unroll
        for (int j = 0; j < 4; ++j) {
          const int d = (wn + j * 16 + lm) & 63;
          base[d] = f2b(acc[i][j][r] * sc);
        }
      }
  } else if (seg < 4) {
    // ---- geo: RoPE in-register, write d in [64,128) ----
    u16* dst = (seg == 2) ? Qb : Kb;
    const float sc = (seg == 2) ? SC : 1.0f;
    const float inv0 = __powf(10000.0f, -(float)(2 * lm) * (1.0f / 64.0f));
    const float inv1 = __powf(10000.0f, -(float)(2 * (16 + lm)) * (1.0f / 64.0f));
#pragma unroll
    for (int i = 0; i < 4; ++i)
#pragma unroll
      for (int r = 0; r < 4; ++r) {
        const int s = sbase + wm + i * 16 + quad * 4 + r;
        float sn0, cs0, sn1, cs1;
        __sincosf((float)s * inv0, &sn0, &cs0);
        __sincosf((float)s * inv1, &sn1, &cs1);
        const float x1a = acc[i][0][r], x2a = acc[i][2][r];  // f0 = lm
        const float x1b = acc[i][1][r], x2b = acc[i][3][r];  // f0 = 16+lm
        u16* base = dst + (bhQ * 2048 + s) * 128 + 64;
        base[lm]      = f2b((x1a * cs0 - x2a * sn0) * sc);
        base[16 + lm] = f2b((x1b * cs1 - x2b * sn1) * sc);
        base[32 + lm] = f2b((x1a * sn0 + x2a * cs0) * sc);
        base[48 + lm] = f2b((x1b * sn1 + x2b * cs1) * sc);
      }
  } else {
    // ---- V: stage TRANSPOSED [d][s] swizzled, write coalesced VT rows -------
    const int hv = (bn - 4096) >> 7;   // one head per tile
    const size_t bh = (size_t)b * 16 + hv;
#pragma unroll
    for (int i = 0; i < 4; ++i)
#pragma unroll
      for (int r = 0; r < 4; ++r) {
        const int sr = wm + i * 16 + quad * 4 + r;
#pragma unroll
        for (int j = 0; j < 4; ++j) {
          const int d = wn + j * 16 + lm;
          sh[d * 128 + (((sr >> 3) ^ (d & 7)) << 3) + (sr & 7)] = f2b(acc[i][j][r]);
        }
      }
    __syncthreads();
#pragma unroll
    for (int it = 0; it < 8; ++it) {
      const int idx = it * 256 + tid;
      const int d = idx >> 4;      // 0..127
      const int ch = idx & 15;     // 8-s chunk
      bf16x8 v = *(const bf16x8*)(sh + d * 128 + ((ch ^ (d & 7)) << 3));
      *(bf16x8*)(VT + (bh * 128 + d) * 2048 + sbase + ch * 8) = v;
    }
  }
}

// ---------------- fused causal attention v9 (ACCEPTED final) ------------------
// XCD-affinity block remap (8x L2-shred fix, R6) + single-buffer 3 blocks/CU +
// MFMA row-sum (P @ ones) + T2 chunk swizzles + setprio. v10-v12 arc closed:
// the kernel is latency/occupancy-bound; fragment-sharing fusions lose to the
// occupancy they cost.
__global__ __launch_bounds__(256, 3) void attn_v9(const u16* __restrict__ Q,
                                                  const u16* __restrict__ K,
                                                  const u16* __restrict__ VT,
                                                  u16* __restrict__ O) {
  constexpr int S = 2048;
  constexpr int D = 128;
  __shared__ u16 Ks[64 * 128];  // chunk-swizzled
  __shared__ u16 Vs[128 * 64];  // VT tile [d][s_local], chunk-swizzled
  __shared__ u16 Ps[64 * 72];   // wave-private rows; padded stride 72
  const int linear = blockIdx.x + (blockIdx.y << 4);
  const int xcd = linear & 7;
  const int slot = linear >> 3;          // 0..63
  const int bh = (xcd << 2) + (slot >> 4);
  const int bx = slot & 15;
  const int b = bh >> 4, h = bh & 15;
  const int tid = threadIdx.x, wid = tid >> 6, lane = tid & 63;
  const int lm = lane & 15, quad = lane >> 4;
  const int rx = lm & 7;
  const int wrow = wid * 16;

  const u16* Kbh = K + (size_t)bh * S * D;
  const u16* Vbh = VT + (size_t)bh * D * S;

  const bf16x8 vones = {16256, 16256, 16256, 16256, 16256, 16256, 16256, 16256};  // bf16 1.0

#pragma unroll 1
  for (int pass = 0; pass < 2; ++pass) {
    const int qt = pass == 0 ? bx : 31 - bx;

    bf16x8 aq[4];
#pragma unroll
    for (int ks = 0; ks < 4; ++ks)
      aq[ks] = *(const bf16x8*)(Q + ((size_t)bh * S + (size_t)qt * 64 + wrow + lm) * D +
                                ks * 32 + quad * 8);

    f32x4 zero = {0.f, 0.f, 0.f, 0.f};
    f32x4 lsum = zero;
    f32x4 oacc[8];
#pragma unroll
    for (int t = 0; t < 8; ++t) oacc[t] = zero;

#pragma unroll 1
    for (int kt = 0; kt <= qt; ++kt) {
      __syncthreads();  // prior iteration's readers done with Ks/Vs
      const u16* Kt = Kbh + (size_t)kt * 64 * D;
      const u16* Vt = Vbh + (size_t)kt * 64;
#pragma unroll
      for (int it = 0; it < 4; ++it) {
        int c = it * 256 + tid;
        int row = c >> 4, u = c & 15;
        g2l16(Kt + (size_t)row * 128 + (size_t)(u ^ (row & 7)) * 8, Ks + c * 8);
      }
#pragma unroll
      for (int it = 0; it < 4; ++it) {
        int c = it * 256 + tid;
        int row = c >> 3, u = c & 7;
        g2l16(Vt + (size_t)row * S + (size_t)(u ^ (row & 7)) * 8, Vs + c * 8);
      }
      __syncthreads();  // barrier drains vmcnt: staged data visible

      // S-tile = Q K^T
      f32x4 sc[4];
#pragma unroll
      for (int j = 0; j < 4; ++j) sc[j] = zero;
      __builtin_amdgcn_s_setprio(1);
#pragma unroll
      for (int ks = 0; ks < 4; ++ks) {
        const int kc = ks * 4 + quad;
#pragma unroll
        for (int j = 0; j < 4; ++j) {
          bf16x8 bk = *(const bf16x8*)(Ks + (((j * 16 + lm) * 16 + (kc ^ rx)) * 8));
          sc[j] = MFMA32(aq[ks], bk, sc[j]);
        }
      }
      __builtin_amdgcn_s_setprio(0);

      const bool diag = (kt == qt);
#pragma unroll
      for (int r = 0; r < 4; ++r) {
        const int qcol = wrow + quad * 4 + r;
        const int prow = (wrow + quad * 4 + r) * 72;
#pragma unroll
        for (int j = 0; j < 4; ++j) {
          float p = __builtin_amdgcn_exp2f(fminf(sc[j][r], 30.0f));
          if (diag && (j * 16 + lm > qcol)) p = 0.f;
          Ps[prow + j * 16 + lm] = f2b(p);
        }
      }
      // no barrier: Ps rows are wave-private (proven R4)

      // O += P @ V ; row-sum += P @ ones
      __builtin_amdgcn_s_setprio(1);
#pragma unroll
      for (int ks = 0; ks < 2; ++ks) {
        bf16x8 ap = *(const bf16x8*)(Ps + (wrow + lm) * 72 + ks * 32 + quad * 8);
        const int kc = ks * 4 + quad;
        lsum = MFMA32(ap, vones, lsum);
#pragma unroll
        for (int t = 0; t < 8; ++t) {
          bf16x8 bv = *(const bf16x8*)(Vs + (((t * 16 + lm) * 8 + (kc ^ rx)) * 8));
          oacc[t] = MFMA32(ap, bv, oacc[t]);
        }
      }
      __builtin_amdgcn_s_setprio(0);
    }

#pragma unroll
    for (int r = 0; r < 4; ++r) {
      float inv = 1.0f / lsum[r];
      const int srow = qt * 64 + wrow + quad * 4 + r;
      u16* Orow = O + ((size_t)b * S + srow) * 2048 + h * 128;
#pragma unroll
      for (int t = 0; t < 8; ++t) Orow[t * 16 + lm] = f2b(oacc[t][r] * inv);
    }
  }
}

extern "C" void kernel_launch(void* const* d_in, const int* in_sizes, int n_in,
                              void* d_out, int out_size, void* d_ws, size_t ws_size,
                              hipStream_t stream) {
  const float* x      = (const float*)d_in[0];
  const float* Wq_sem = (const float*)d_in[1];
  const float* Wk_sem = (const float*)d_in[2];
  const float* Wq_geo = (const float*)d_in[3];
  const float* Wk_geo = (const float*)d_in[4];
  const float* Wv     = (const float*)d_in[5];
  const float* Wo     = (const float*)d_in[6];

  char* ws = (char*)d_ws;
  // layout (bytes):
  //   [0, 16M)          xb  (x bf16, 4096x2048)
  //   [16M, 41.2M)      Wall (6144x2048 bf16)   -> later reused as O
  //   [41.2M, 49.6M)    Wob  (2048x2048 bf16)
  //   [49.6M, 66.3M)    Qb   (bf16, 32 heads x 2048 x 128)
  // d_out (33.5MB) used as scratch for K (16.7M) + VT (16.7M) until final GEMM.
  u16* xb   = (u16*)(ws);
  u16* Wall = (u16*)(ws + 16777216);
  u16* Wob  = (u16*)(ws + 16777216 + 25165824);
  u16* Qb   = (u16*)(ws + 16777216 + 25165824 + 8388608);
  u16* Ob   = Wall;
  u16* Kb   = (u16*)d_out;
  u16* VT   = (u16*)((char*)d_out + 16777216);

  // all casts in one launch
  cast_all<<<24576, 256, 0, stream>>>(x, Wq_sem, Wk_sem, Wq_geo, Wk_geo, Wv, Wo,
                                      xb, Wall, Wob);

  // fused QKV projection + RoPE + head rearrange: writes Q/K/VT directly
  gemm_qkv<<<dim3(48, 32), 256, 0, stream>>>(xb, Wall, Qb, Kb, VT);

  // causal flash attention -> O (B*S, 2048) bf16
  attn_v9<<<dim3(16, 32), 256, 0, stream>>>(Qb, Kb, VT, Ob);

  // final projection: out = O @ Wo^T  (M=4096, N=2048, K=2048), fp32 out
  gemm_bt<false><<<dim3(16, 32), 256, 0, stream>>>(Ob, Wob, d_out, 2048, 2048);
}

// Round 16
// 338.374 us; speedup vs baseline: 1.5171x; 1.0675x over previous
//
#include <hip/hip_runtime.h>
#include <cstdint>
#include <cstddef>

typedef unsigned short u16;
typedef __attribute__((ext_vector_type(8))) short bf16x8;
typedef __attribute__((ext_vector_type(4))) float f32x4;

#define MFMA32(a, b, c) __builtin_amdgcn_mfma_f32_16x16x32_bf16(a, b, c, 0, 0, 0)

__device__ __forceinline__ u16 f2b(float f) {
  union { float f; unsigned u; } v; v.f = f;
  unsigned u = v.u;
  return (u16)((u + 0x7fffu + ((u >> 16) & 1u)) >> 16);
}
__device__ __forceinline__ float b2f(u16 h) {
  union { unsigned u; float f; } v; v.u = ((unsigned)h) << 16;
  return v.f;
}

// async global->LDS, 16B per lane. LDS dest must be wave-uniform base + lane*16.
__device__ __forceinline__ void g2l16(const void* g, void* l) {
  __builtin_amdgcn_global_load_lds((__attribute__((address_space(1))) void*)(g),
                                   (__attribute__((address_space(3))) void*)(l), 16, 0, 0);
}

// ---------------- ALL fp32->bf16 casts in one launch --------------------------
__global__ __launch_bounds__(256) void cast_all(const float* __restrict__ x,
                                                const float* __restrict__ W0,
                                                const float* __restrict__ W1,
                                                const float* __restrict__ W2,
                                                const float* __restrict__ W3,
                                                const float* __restrict__ Wv,
                                                const float* __restrict__ Wo,
                                                u16* __restrict__ xb,
                                                u16* __restrict__ Wall,
                                                u16* __restrict__ Wob) {
  const int blk = blockIdx.x;
  const float* src;
  u16* dst;
  int li;
  if (blk < 8192) {
    src = x; dst = xb; li = blk * 256 + threadIdx.x;
  } else if (blk < 16384) {
    const int s = (blk - 8192) >> 11;
    src = s == 0 ? W0 : s == 1 ? W1 : s == 2 ? W2 : W3;
    dst = Wall + (size_t)s * 2097152;
    li = ((blk - 8192) & 2047) * 256 + threadIdx.x;
  } else if (blk < 20480) {
    src = Wv; dst = Wall + (size_t)4 * 2097152;
    li = (blk - 16384) * 256 + threadIdx.x;
  } else {
    src = Wo; dst = Wob;
    li = (blk - 20480) * 256 + threadIdx.x;
  }
  float4 v = ((const float4*)src)[li];
  ushort4 r;
  r.x = f2b(v.x); r.y = f2b(v.y); r.z = f2b(v.z); r.w = f2b(v.w);
  ((ushort4*)dst)[li] = r;
}

// ---------------- C = A @ B^T  128x128 tile (m97 structure; final projection) -
template <bool BF16_OUT>
__global__ __launch_bounds__(256) void gemm_bt(const u16* __restrict__ A,
                                               const u16* __restrict__ B,
                                               void* __restrict__ C, int N, int K) {
  __shared__ u16 As[128 * 64];
  __shared__ u16 Bs[128 * 64];
  const int tid = threadIdx.x;
  const int wid = tid >> 6;
  const int lane = tid & 63;
  const int lm = lane & 15;
  const int quad = lane >> 4;
  const int r3 = lm & 7;
  const int wm = (wid & 1) * 64;
  const int wn = (wid >> 1) * 64;
  const int bm = blockIdx.y * 128;
  const int bn = blockIdx.x * 128;

  const u16* Ab = A + (size_t)bm * K;
  const u16* Bb = B + (size_t)bn * K;

  f32x4 zero = {0.f, 0.f, 0.f, 0.f};
  f32x4 acc[4][4];
#pragma unroll
  for (int i = 0; i < 4; ++i)
#pragma unroll
    for (int j = 0; j < 4; ++j) acc[i][j] = zero;

  for (int k0 = 0; k0 < K; k0 += 64) {
#pragma unroll
    for (int it = 0; it < 4; ++it) {
      int c = it * 256 + tid;
      int rg = c >> 6, rw = (c >> 3) & 7, u = c & 7;
      int row = rg * 8 + rw;
      int chd = u ^ rw;
      g2l16(Ab + (size_t)row * K + k0 + chd * 8, As + c * 8);
      g2l16(Bb + (size_t)row * K + k0 + chd * 8, Bs + c * 8);
    }
    __syncthreads();
#pragma unroll
    for (int ks = 0; ks < 2; ++ks) {
      bf16x8 a[4], b[4];
      int chd = ks * 4 + quad;
#pragma unroll
      for (int i = 0; i < 4; ++i) {
        int row = wm + i * 16 + lm;
        a[i] = *(const bf16x8*)(As + (((row >> 3) * 64 + r3 * 8 + (chd ^ r3)) * 8));
      }
#pragma unroll
      for (int j = 0; j < 4; ++j) {
        int row = wn + j * 16 + lm;
        b[j] = *(const bf16x8*)(Bs + (((row >> 3) * 64 + r3 * 8 + (chd ^ r3)) * 8));
      }
#pragma unroll
      for (int i = 0; i < 4; ++i)
#pragma unroll
        for (int j = 0; j < 4; ++j)
          acc[i][j] = MFMA32(a[i], b[j], acc[i][j]);
    }
    __syncthreads();
  }

#pragma unroll
  for (int i = 0; i < 4; ++i)
#pragma unroll
    for (int j = 0; j < 4; ++j)
#pragma unroll
      for (int r = 0; r < 4; ++r) {
        int row = bm + wm + i * 16 + quad * 4 + r;
        int col = bn + wn + j * 16 + lm;
        float v = acc[i][j][r];
        if (BF16_OUT)
          ((u16*)C)[(size_t)row * N + col] = f2b(v);
        else
          ((float*)C)[(size_t)row * N + col] = v;
      }
}

// ---------------- QKV GEMM v5: 128x256 8-phase counted-vmcnt + fused epilogue -
// R7's verified 8-phase schedule re-derived for 128x256 tiles: grid becomes
// 32x24 = 768 blocks = EXACTLY 3.0 dispatch rounds at 1 block/CU (R7's 256²
// grid was 384 = 1.5 rounds -> 25% idle tail, why it lost to 128²).
// 8 waves (2Mx4N), wave-tile 64x64, acc[4][4]. LDS 96KB dynamic:
// A dbuf 2x16KB + B dbuf 2x32KB. Stage units of 16KB (A, B.lo, B.hi).
// Phase map per iter (tiles 2i/2i+1 in buf0/buf1; t1=2i+1,t2=2i+2,t3=2i+3):
//   ph0: ld aA(mh0)+bB(nh0) buf0; stage t1.u1   | mm(0,0)
//   ph1: ld bB(nh1);              stage t1.u2   | mm(0,1)
//   ph2: ld aA(mh1)  [buf0 reads END]           | mm(1,1)
//   ph3: stage t2.u0 -> buf0 (sealed ph2-end)   | mm(1,0)  gate vmcnt(2)
//   ph4-7: same on buf1; ph7 stages t3.u0, gate vmcnt(2)
// Gate invariant: at each gate the only younger load is that phase's own
// unit; every unit completes >=2 phases before its buffer is read.
// Epilogue: R10-proven hybrid (sem/geo direct, V swizzled-staged), wave
// geometry identical (64-col regions); V staging 256x128 u16 = 64KB <= 96KB.
__global__ __launch_bounds__(512, 2) void gemm_qkv8(const u16* __restrict__ A,
                                                    const u16* __restrict__ B,
                                                    u16* __restrict__ Qb,
                                                    u16* __restrict__ Kb,
                                                    u16* __restrict__ VT) {
  constexpr int K = 2048;
  const float SC = 0.12751744f;  // (1/sqrt(128)) * log2(e)
  extern __shared__ u16 sh[];    // 96KB: sA 2x8192 u16 | sB 2x16384 u16
  u16* sA = sh;
  u16* sB = sh + 16384;
  const int tid = threadIdx.x;
  const int wid = tid >> 6, lane = tid & 63;
  const int lm = lane & 15, quad = lane >> 4, rx = lm & 7;
  const int wm = (wid >> 2) * 64;   // 0/64   (M offset of wave)
  const int wn = (wid & 3) * 64;    // 0..192 (N offset of wave)
  const int bm = blockIdx.y * 128;
  const int bn = blockIdx.x * 256;
  const u16* Ablk = A + (size_t)bm * K;
  const u16* Bblk = B + (size_t)bn * K;

  f32x4 zero = {0.f, 0.f, 0.f, 0.f};
  f32x4 acc[4][4];
#pragma unroll
  for (int i = 0; i < 4; ++i)
#pragma unroll
    for (int j = 0; j < 4; ++j) acc[i][j] = zero;

  bf16x8 aA[2][2];     // [M-frag within quadrant][ks]
  bf16x8 bB[2][2][2];  // [nh][N-frag][ks] — both nh groups held

  // stage one 16KB unit (ut 0=A, 1=B rows 0-127, 2=B rows 128-255) of tile st
  auto stageu = [&](int st, int ut) {
    const int k0 = st << 6;
    const int bf = st & 1;
    const u16* src;
    u16* dst;
    int rowbase;
    if (ut == 0) { src = Ablk; rowbase = 0; dst = sA + bf * 8192; }
    else { src = Bblk; rowbase = (ut - 1) << 7; dst = sB + bf * 16384 + ((ut - 1) << 13); }
#pragma unroll
    for (int it = 0; it < 2; ++it) {
      const int c = it * 512 + tid;  // 0..1023 chunks of 16B
      const int r = c >> 3, u = c & 7;
      g2l16(src + (size_t)(rowbase + r) * K + k0 + ((u ^ (r & 7)) << 3), dst + (size_t)c * 8);
    }
  };
  auto ldA = [&](int bf, int mh) {
    const u16* base = sA + bf * 8192;
#pragma unroll
    for (int ii = 0; ii < 2; ++ii)
#pragma unroll
      for (int ks = 0; ks < 2; ++ks) {
        const int row = wm + mh * 32 + ii * 16 + lm;  // row&7 == rx
        aA[ii][ks] = *(const bf16x8*)(base + ((row * 8 + ((ks * 4 + quad) ^ rx)) << 3));
      }
  };
  auto ldB = [&](int bf, int nh) {
    const u16* base = sB + bf * 16384;
#pragma unroll
    for (int jj = 0; jj < 2; ++jj)
#pragma unroll
      for (int ks = 0; ks < 2; ++ks) {
        const int row = wn + nh * 32 + jj * 16 + lm;  // 0..255
        bB[nh][jj][ks] = *(const bf16x8*)(base + ((row * 8 + ((ks * 4 + quad) ^ rx)) << 3));
      }
  };
  auto mm = [&](int mh, int nh) {
    __builtin_amdgcn_s_setprio(1);
#pragma unroll
    for (int ii = 0; ii < 2; ++ii)
#pragma unroll
      for (int jj = 0; jj < 2; ++jj)
#pragma unroll
        for (int ks = 0; ks < 2; ++ks)
          acc[mh * 2 + ii][nh * 2 + jj] =
              MFMA32(aA[ii][ks], bB[nh][jj][ks], acc[mh * 2 + ii][nh * 2 + jj]);
    __builtin_amdgcn_s_setprio(0);
  };

  const int NT = K >> 6;    // 32
  const int NIT = NT >> 1;  // 16

  // prologue: tile0 fully + tile1 u0 (8 loads/thread)
  stageu(0, 0); stageu(0, 1); stageu(0, 2); stageu(1, 0);
  asm volatile("s_waitcnt vmcnt(2)" ::: "memory");  // tile0 complete
  __builtin_amdgcn_s_barrier();

#pragma unroll 1
  for (int i = 0; i < NIT; ++i) {
    const int t1 = 2 * i + 1, t2 = 2 * i + 2, t3 = 2 * i + 3;
    // ph0
    ldA(0, 0); ldB(0, 0);
    stageu(t1, 1);  // t1 <= NT-1 always
    __builtin_amdgcn_s_barrier();
    mm(0, 0);
    __builtin_amdgcn_s_barrier();
    // ph1
    ldB(0, 1);
    stageu(t1, 2);
    __builtin_amdgcn_s_barrier();
    mm(0, 1);
    __builtin_amdgcn_s_barrier();
    // ph2 (buf0 reads END)
    ldA(0, 1);
    __builtin_amdgcn_s_barrier();
    mm(1, 1);
    __builtin_amdgcn_s_barrier();
    // ph3: stage t2.u0 -> buf0; gate: tile t1 complete
    {
      const bool st = (t2 < NT);
      if (st) stageu(t2, 0);
      __builtin_amdgcn_s_barrier();
      mm(1, 0);
      if (st) asm volatile("s_waitcnt vmcnt(2)" ::: "memory");
      else    asm volatile("s_waitcnt vmcnt(0)" ::: "memory");
      __builtin_amdgcn_s_barrier();
    }
    // ph4
    ldA(1, 0); ldB(1, 0);
    if (t2 < NT) stageu(t2, 1);
    __builtin_amdgcn_s_barrier();
    mm(0, 0);
    __builtin_amdgcn_s_barrier();
    // ph5
    ldB(1, 1);
    if (t2 < NT) stageu(t2, 2);
    __builtin_amdgcn_s_barrier();
    mm(0, 1);
    __builtin_amdgcn_s_barrier();
    // ph6 (buf1 reads END)
    ldA(1, 1);
    __builtin_amdgcn_s_barrier();
    mm(1, 1);
    __builtin_amdgcn_s_barrier();
    // ph7: stage t3.u0 -> buf1; gate: tile t2 complete
    {
      const bool st = (t3 < NT);
      if (st) stageu(t3, 0);
      __builtin_amdgcn_s_barrier();
      mm(1, 0);
      if (st) asm volatile("s_waitcnt vmcnt(2)" ::: "memory");
      else    asm volatile("s_waitcnt vmcnt(0)" ::: "memory");
      __builtin_amdgcn_s_barrier();
    }
  }

  // ---------------- fused RoPE/rearrange epilogue (R10 hybrid, transplanted) --
  const int seg = bn >> 10;  // uniform per block (BN=256 divides 1024)
  const int b = bm >> 11;
  const int sbase = bm & 2047;
  const int h = ((bn + wn) >> 6) & 15;  // head for Q/K segments (per-wave)
  const size_t bhQ = (size_t)b * 16 + h;

  if (seg < 2) {
    // ---- sem: direct copy ----
    u16* dst = (seg == 0) ? Qb : Kb;
    const float sc = (seg == 0) ? SC : 1.0f;
#pragma unroll
    for (int i = 0; i < 4; ++i)
#pragma unroll
      for (int r = 0; r < 4; ++r) {
        const int s = sbase + wm + i * 16 + quad * 4 + r;
        u16* base = dst + (bhQ * 2048 + s) * 128;
#pragma unroll
        for (int j = 0; j < 4; ++j) {
          const int d = (wn + j * 16 + lm) & 63;
          base[d] = f2b(acc[i][j][r] * sc);
        }
      }
  } else if (seg < 4) {
    // ---- geo: RoPE in-register, write d in [64,128) ----
    u16* dst = (seg == 2) ? Qb : Kb;
    const float sc = (seg == 2) ? SC : 1.0f;
    const float inv0 = __powf(10000.0f, -(float)(2 * lm) * (1.0f / 64.0f));
    const float inv1 = __powf(10000.0f, -(float)(2 * (16 + lm)) * (1.0f / 64.0f));
#pragma unroll
    for (int i = 0; i < 4; ++i)
#pragma unroll
      for (int r = 0; r < 4; ++r) {
        const int s = sbase + wm + i * 16 + quad * 4 + r;
        float sn0, cs0, sn1, cs1;
        __sincosf((float)s * inv0, &sn0, &cs0);
        __sincosf((float)s * inv1, &sn1, &cs1);
        const float x1a = acc[i][0][r], x2a = acc[i][2][r];  // f0 = lm
        const float x1b = acc[i][1][r], x2b = acc[i][3][r];  // f0 = 16+lm
        u16* base = dst + (bhQ * 2048 + s) * 128 + 64;
        base[lm]      = f2b((x1a * cs0 - x2a * sn0) * sc);
        base[16 + lm] = f2b((x1b * cs1 - x2b * sn1) * sc);
        base[32 + lm] = f2b((x1a * sn0 + x2a * cs0) * sc);
        base[48 + lm] = f2b((x1b * sn1 + x2b * cs1) * sc);
      }
  } else {
    // ---- V: stage TRANSPOSED [d][s] swizzled (2 heads), coalesced VT rows ---
    const int hv0 = (bn - 4096) >> 7;  // first head of this tile
#pragma unroll
    for (int i = 0; i < 4; ++i)
#pragma unroll
      for (int r = 0; r < 4; ++r) {
        const int sr = wm + i * 16 + quad * 4 + r;  // 0..127
#pragma unroll
        for (int j = 0; j < 4; ++j) {
          const int d = wn + j * 16 + lm;  // 0..255
          sh[d * 128 + (((sr >> 3) ^ (d & 7)) << 3) + (sr & 7)] = f2b(acc[i][j][r]);
        }
      }
    __syncthreads();
#pragma unroll
    for (int it = 0; it < 8; ++it) {
      const int idx = it * 512 + tid;  // 0..4095
      const int d = idx >> 4;          // 0..255
      const int ch = idx & 15;         // 8-s chunk
      bf16x8 v = *(const bf16x8*)(sh + d * 128 + ((ch ^ (d & 7)) << 3));
      const size_t bh = (size_t)b * 16 + hv0 + (d >> 7);
      *(bf16x8*)(VT + (bh * 128 + (d & 127)) * 2048 + sbase + ch * 8) = v;
    }
  }
}

// ---------------- fused causal attention v9 (ACCEPTED final) ------------------
__global__ __launch_bounds__(256, 3) void attn_v9(const u16* __restrict__ Q,
                                                  const u16* __restrict__ K,
                                                  const u16* __restrict__ VT,
                                                  u16* __restrict__ O) {
  constexpr int S = 2048;
  constexpr int D = 128;
  __shared__ u16 Ks[64 * 128];  // chunk-swizzled
  __shared__ u16 Vs[128 * 64];  // VT tile [d][s_local], chunk-swizzled
  __shared__ u16 Ps[64 * 72];   // wave-private rows; padded stride 72
  const int linear = blockIdx.x + (blockIdx.y << 4);
  const int xcd = linear & 7;
  const int slot = linear >> 3;          // 0..63
  const int bh = (xcd << 2) + (slot >> 4);
  const int bx = slot & 15;
  const int b = bh >> 4, h = bh & 15;
  const int tid = threadIdx.x, wid = tid >> 6, lane = tid & 63;
  const int lm = lane & 15, quad = lane >> 4;
  const int rx = lm & 7;
  const int wrow = wid * 16;

  const u16* Kbh = K + (size_t)bh * S * D;
  const u16* Vbh = VT + (size_t)bh * D * S;

  const bf16x8 vones = {16256, 16256, 16256, 16256, 16256, 16256, 16256, 16256};  // bf16 1.0

#pragma unroll 1
  for (int pass = 0; pass < 2; ++pass) {
    const int qt = pass == 0 ? bx : 31 - bx;

    bf16x8 aq[4];
#pragma unroll
    for (int ks = 0; ks < 4; ++ks)
      aq[ks] = *(const bf16x8*)(Q + ((size_t)bh * S + (size_t)qt * 64 + wrow + lm) * D +
                                ks * 32 + quad * 8);

    f32x4 zero = {0.f, 0.f, 0.f, 0.f};
    f32x4 lsum = zero;
    f32x4 oacc[8];
#pragma unroll
    for (int t = 0; t < 8; ++t) oacc[t] = zero;

#pragma unroll 1
    for (int kt = 0; kt <= qt; ++kt) {
      __syncthreads();  // prior iteration's readers done with Ks/Vs
      const u16* Kt = Kbh + (size_t)kt * 64 * D;
      const u16* Vt = Vbh + (size_t)kt * 64;
#pragma unroll
      for (int it = 0; it < 4; ++it) {
        int c = it * 256 + tid;
        int row = c >> 4, u = c & 15;
        g2l16(Kt + (size_t)row * 128 + (size_t)(u ^ (row & 7)) * 8, Ks + c * 8);
      }
#pragma unroll
      for (int it = 0; it < 4; ++it) {
        int c = it * 256 + tid;
        int row = c >> 3, u = c & 7;
        g2l16(Vt + (size_t)row * S + (size_t)(u ^ (row & 7)) * 8, Vs + c * 8);
      }
      __syncthreads();  // barrier drains vmcnt: staged data visible

      // S-tile = Q K^T
      f32x4 sc[4];
#pragma unroll
      for (int j = 0; j < 4; ++j) sc[j] = zero;
      __builtin_amdgcn_s_setprio(1);
#pragma unroll
      for (int ks = 0; ks < 4; ++ks) {
        const int kc = ks * 4 + quad;
#pragma unroll
        for (int j = 0; j < 4; ++j) {
          bf16x8 bk = *(const bf16x8*)(Ks + (((j * 16 + lm) * 16 + (kc ^ rx)) * 8));
          sc[j] = MFMA32(aq[ks], bk, sc[j]);
        }
      }
      __builtin_amdgcn_s_setprio(0);

      const bool diag = (kt == qt);
#pragma unroll
      for (int r = 0; r < 4; ++r) {
        const int qcol = wrow + quad * 4 + r;
        const int prow = (wrow + quad * 4 + r) * 72;
#pragma unroll
        for (int j = 0; j < 4; ++j) {
          float p = __builtin_amdgcn_exp2f(fminf(sc[j][r], 30.0f));
          if (diag && (j * 16 + lm > qcol)) p = 0.f;
          Ps[prow + j * 16 + lm] = f2b(p);
        }
      }
      // no barrier: Ps rows are wave-private (proven R4)

      // O += P @ V ; row-sum += P @ ones
      __builtin_amdgcn_s_setprio(1);
#pragma unroll
      for (int ks = 0; ks < 2; ++ks) {
        bf16x8 ap = *(const bf16x8*)(Ps + (wrow + lm) * 72 + ks * 32 + quad * 8);
        const int kc = ks * 4 + quad;
        lsum = MFMA32(ap, vones, lsum);
#pragma unroll
        for (int t = 0; t < 8; ++t) {
          bf16x8 bv = *(const bf16x8*)(Vs + (((t * 16 + lm) * 8 + (kc ^ rx)) * 8));
          oacc[t] = MFMA32(ap, bv, oacc[t]);
        }
      }
      __builtin_amdgcn_s_setprio(0);
    }

#pragma unroll
    for (int r = 0; r < 4; ++r) {
      float inv = 1.0f / lsum[r];
      const int srow = qt * 64 + wrow + quad * 4 + r;
      u16* Orow = O + ((size_t)b * S + srow) * 2048 + h * 128;
#pragma unroll
      for (int t = 0; t < 8; ++t) Orow[t * 16 + lm] = f2b(oacc[t][r] * inv);
    }
  }
}

extern "C" void kernel_launch(void* const* d_in, const int* in_sizes, int n_in,
                              void* d_out, int out_size, void* d_ws, size_t ws_size,
                              hipStream_t stream) {
  const float* x      = (const float*)d_in[0];
  const float* Wq_sem = (const float*)d_in[1];
  const float* Wk_sem = (const float*)d_in[2];
  const float* Wq_geo = (const float*)d_in[3];
  const float* Wk_geo = (const float*)d_in[4];
  const float* Wv     = (const float*)d_in[5];
  const float* Wo     = (const float*)d_in[6];

  char* ws = (char*)d_ws;
  // layout (bytes):
  //   [0, 16M)          xb  (x bf16, 4096x2048)
  //   [16M, 41.2M)      Wall (6144x2048 bf16)   -> later reused as O
  //   [41.2M, 49.6M)    Wob  (2048x2048 bf16)
  //   [49.6M, 66.3M)    Qb   (bf16, 32 heads x 2048 x 128)
  // d_out (33.5MB) used as scratch for K (16.7M) + VT (16.7M) until final GEMM.
  u16* xb   = (u16*)(ws);
  u16* Wall = (u16*)(ws + 16777216);
  u16* Wob  = (u16*)(ws + 16777216 + 25165824);
  u16* Qb   = (u16*)(ws + 16777216 + 25165824 + 8388608);
  u16* Ob   = Wall;
  u16* Kb   = (u16*)d_out;
  u16* VT   = (u16*)((char*)d_out + 16777216);

  hipFuncSetAttribute((const void*)gemm_qkv8,
                      hipFuncAttributeMaxDynamicSharedMemorySize, 98304);

  // all casts in one launch
  cast_all<<<24576, 256, 0, stream>>>(x, Wq_sem, Wk_sem, Wq_geo, Wk_geo, Wv, Wo,
                                      xb, Wall, Wob);

  // fused QKV projection + RoPE + head rearrange: 128x256 8-phase, 768 blocks
  gemm_qkv8<<<dim3(24, 32), 512, 98304, stream>>>(xb, Wall, Qb, Kb, VT);

  // causal flash attention -> O (B*S, 2048) bf16
  attn_v9<<<dim3(16, 32), 256, 0, stream>>>(Qb, Kb, VT, Ob);

  // final projection: out = O @ Wo^T  (M=4096, N=2048, K=2048), fp32 out
  gemm_bt<false><<<dim3(16, 32), 256, 0, stream>>>(Ob, Wob, d_out, 2048, 2048);
}

// Round 17
// 337.242 us; speedup vs baseline: 1.5222x; 1.0034x over previous
//
#include <hip/hip_runtime.h>
#include <cstdint>
#include <cstddef>

typedef unsigned short u16;
typedef __attribute__((ext_vector_type(8))) short bf16x8;
typedef __attribute__((ext_vector_type(4))) float f32x4;

#define MFMA32(a, b, c) __builtin_amdgcn_mfma_f32_16x16x32_bf16(a, b, c, 0, 0, 0)

__device__ __forceinline__ u16 f2b(float f) {
  union { float f; unsigned u; } v; v.f = f;
  unsigned u = v.u;
  return (u16)((u + 0x7fffu + ((u >> 16) & 1u)) >> 16);
}
__device__ __forceinline__ float b2f(u16 h) {
  union { unsigned u; float f; } v; v.u = ((unsigned)h) << 16;
  return v.f;
}

// async global->LDS, 16B per lane. LDS dest must be wave-uniform base + lane*16.
__device__ __forceinline__ void g2l16(const void* g, void* l) {
  __builtin_amdgcn_global_load_lds((__attribute__((address_space(1))) void*)(g),
                                   (__attribute__((address_space(3))) void*)(l), 16, 0, 0);
}

// ---------------- ALL fp32->bf16 casts in one launch --------------------------
__global__ __launch_bounds__(256) void cast_all(const float* __restrict__ x,
                                                const float* __restrict__ W0,
                                                const float* __restrict__ W1,
                                                const float* __restrict__ W2,
                                                const float* __restrict__ W3,
                                                const float* __restrict__ Wv,
                                                const float* __restrict__ Wo,
                                                u16* __restrict__ xb,
                                                u16* __restrict__ Wall,
                                                u16* __restrict__ Wob) {
  const int blk = blockIdx.x;
  const float* src;
  u16* dst;
  int li;
  if (blk < 8192) {
    src = x; dst = xb; li = blk * 256 + threadIdx.x;
  } else if (blk < 16384) {
    const int s = (blk - 8192) >> 11;
    src = s == 0 ? W0 : s == 1 ? W1 : s == 2 ? W2 : W3;
    dst = Wall + (size_t)s * 2097152;
    li = ((blk - 8192) & 2047) * 256 + threadIdx.x;
  } else if (blk < 20480) {
    src = Wv; dst = Wall + (size_t)4 * 2097152;
    li = (blk - 16384) * 256 + threadIdx.x;
  } else {
    src = Wo; dst = Wob;
    li = (blk - 20480) * 256 + threadIdx.x;
  }
  float4 v = ((const float4*)src)[li];
  ushort4 r;
  r.x = f2b(v.x); r.y = f2b(v.y); r.z = f2b(v.z); r.w = f2b(v.w);
  ((ushort4*)dst)[li] = r;
}

// ---------------- QKV GEMM v5: 128x256 8-phase counted-vmcnt + fused epilogue -
// (R16-verified: 113.5us, MfmaUtil 38-39%, VGPR 80, no spill.)
// 768 blocks = exactly 3.0 dispatch rounds at 1 block/CU.
__global__ __launch_bounds__(512, 2) void gemm_qkv8(const u16* __restrict__ A,
                                                    const u16* __restrict__ B,
                                                    u16* __restrict__ Qb,
                                                    u16* __restrict__ Kb,
                                                    u16* __restrict__ VT) {
  constexpr int K = 2048;
  const float SC = 0.12751744f;  // (1/sqrt(128)) * log2(e)
  extern __shared__ u16 sh[];    // 96KB: sA 2x8192 u16 | sB 2x16384 u16
  u16* sA = sh;
  u16* sB = sh + 16384;
  const int tid = threadIdx.x;
  const int wid = tid >> 6, lane = tid & 63;
  const int lm = lane & 15, quad = lane >> 4, rx = lm & 7;
  const int wm = (wid >> 2) * 64;   // 0/64   (M offset of wave)
  const int wn = (wid & 3) * 64;    // 0..192 (N offset of wave)
  const int bm = blockIdx.y * 128;
  const int bn = blockIdx.x * 256;
  const u16* Ablk = A + (size_t)bm * K;
  const u16* Bblk = B + (size_t)bn * K;

  f32x4 zero = {0.f, 0.f, 0.f, 0.f};
  f32x4 acc[4][4];
#pragma unroll
  for (int i = 0; i < 4; ++i)
#pragma unroll
    for (int j = 0; j < 4; ++j) acc[i][j] = zero;

  bf16x8 aA[2][2];     // [M-frag within quadrant][ks]
  bf16x8 bB[2][2][2];  // [nh][N-frag][ks] — both nh groups held

  auto stageu = [&](int st, int ut) {
    const int k0 = st << 6;
    const int bf = st & 1;
    const u16* src;
    u16* dst;
    int rowbase;
    if (ut == 0) { src = Ablk; rowbase = 0; dst = sA + bf * 8192; }
    else { src = Bblk; rowbase = (ut - 1) << 7; dst = sB + bf * 16384 + ((ut - 1) << 13); }
#pragma unroll
    for (int it = 0; it < 2; ++it) {
      const int c = it * 512 + tid;  // 0..1023 chunks of 16B
      const int r = c >> 3, u = c & 7;
      g2l16(src + (size_t)(rowbase + r) * K + k0 + ((u ^ (r & 7)) << 3), dst + (size_t)c * 8);
    }
  };
  auto ldA = [&](int bf, int mh) {
    const u16* base = sA + bf * 8192;
#pragma unroll
    for (int ii = 0; ii < 2; ++ii)
#pragma unroll
      for (int ks = 0; ks < 2; ++ks) {
        const int row = wm + mh * 32 + ii * 16 + lm;  // row&7 == rx
        aA[ii][ks] = *(const bf16x8*)(base + ((row * 8 + ((ks * 4 + quad) ^ rx)) << 3));
      }
  };
  auto ldB = [&](int bf, int nh) {
    const u16* base = sB + bf * 16384;
#pragma unroll
    for (int jj = 0; jj < 2; ++jj)
#pragma unroll
      for (int ks = 0; ks < 2; ++ks) {
        const int row = wn + nh * 32 + jj * 16 + lm;  // 0..255
        bB[nh][jj][ks] = *(const bf16x8*)(base + ((row * 8 + ((ks * 4 + quad) ^ rx)) << 3));
      }
  };
  auto mm = [&](int mh, int nh) {
    __builtin_amdgcn_s_setprio(1);
#pragma unroll
    for (int ii = 0; ii < 2; ++ii)
#pragma unroll
      for (int jj = 0; jj < 2; ++jj)
#pragma unroll
        for (int ks = 0; ks < 2; ++ks)
          acc[mh * 2 + ii][nh * 2 + jj] =
              MFMA32(aA[ii][ks], bB[nh][jj][ks], acc[mh * 2 + ii][nh * 2 + jj]);
    __builtin_amdgcn_s_setprio(0);
  };

  const int NT = K >> 6;    // 32
  const int NIT = NT >> 1;  // 16

  stageu(0, 0); stageu(0, 1); stageu(0, 2); stageu(1, 0);
  asm volatile("s_waitcnt vmcnt(2)" ::: "memory");  // tile0 complete
  __builtin_amdgcn_s_barrier();

#pragma unroll 1
  for (int i = 0; i < NIT; ++i) {
    const int t1 = 2 * i + 1, t2 = 2 * i + 2, t3 = 2 * i + 3;
    ldA(0, 0); ldB(0, 0);
    stageu(t1, 1);
    __builtin_amdgcn_s_barrier();
    mm(0, 0);
    __builtin_amdgcn_s_barrier();
    ldB(0, 1);
    stageu(t1, 2);
    __builtin_amdgcn_s_barrier();
    mm(0, 1);
    __builtin_amdgcn_s_barrier();
    ldA(0, 1);
    __builtin_amdgcn_s_barrier();
    mm(1, 1);
    __builtin_amdgcn_s_barrier();
    {
      const bool st = (t2 < NT);
      if (st) stageu(t2, 0);
      __builtin_amdgcn_s_barrier();
      mm(1, 0);
      if (st) asm volatile("s_waitcnt vmcnt(2)" ::: "memory");
      else    asm volatile("s_waitcnt vmcnt(0)" ::: "memory");
      __builtin_amdgcn_s_barrier();
    }
    ldA(1, 0); ldB(1, 0);
    if (t2 < NT) stageu(t2, 1);
    __builtin_amdgcn_s_barrier();
    mm(0, 0);
    __builtin_amdgcn_s_barrier();
    ldB(1, 1);
    if (t2 < NT) stageu(t2, 2);
    __builtin_amdgcn_s_barrier();
    mm(0, 1);
    __builtin_amdgcn_s_barrier();
    ldA(1, 1);
    __builtin_amdgcn_s_barrier();
    mm(1, 1);
    __builtin_amdgcn_s_barrier();
    {
      const bool st = (t3 < NT);
      if (st) stageu(t3, 0);
      __builtin_amdgcn_s_barrier();
      mm(1, 0);
      if (st) asm volatile("s_waitcnt vmcnt(2)" ::: "memory");
      else    asm volatile("s_waitcnt vmcnt(0)" ::: "memory");
      __builtin_amdgcn_s_barrier();
    }
  }

  // ---------------- fused RoPE/rearrange epilogue (R10 hybrid) ----------------
  const int seg = bn >> 10;
  const int b = bm >> 11;
  const int sbase = bm & 2047;
  const int h = ((bn + wn) >> 6) & 15;
  const size_t bhQ = (size_t)b * 16 + h;

  if (seg < 2) {
    u16* dst = (seg == 0) ? Qb : Kb;
    const float sc = (seg == 0) ? SC : 1.0f;
#pragma unroll
    for (int i = 0; i < 4; ++i)
#pragma unroll
      for (int r = 0; r < 4; ++r) {
        const int s = sbase + wm + i * 16 + quad * 4 + r;
        u16* base = dst + (bhQ * 2048 + s) * 128;
#pragma unroll
        for (int j = 0; j < 4; ++j) {
          const int d = (wn + j * 16 + lm) & 63;
          base[d] = f2b(acc[i][j][r] * sc);
        }
      }
  } else if (seg < 4) {
    u16* dst = (seg == 2) ? Qb : Kb;
    const float sc = (seg == 2) ? SC : 1.0f;
    const float inv0 = __powf(10000.0f, -(float)(2 * lm) * (1.0f / 64.0f));
    const float inv1 = __powf(10000.0f, -(float)(2 * (16 + lm)) * (1.0f / 64.0f));
#pragma unroll
    for (int i = 0; i < 4; ++i)
#pragma unroll
      for (int r = 0; r < 4; ++r) {
        const int s = sbase + wm + i * 16 + quad * 4 + r;
        float sn0, cs0, sn1, cs1;
        __sincosf((float)s * inv0, &sn0, &cs0);
        __sincosf((float)s * inv1, &sn1, &cs1);
        const float x1a = acc[i][0][r], x2a = acc[i][2][r];
        const float x1b = acc[i][1][r], x2b = acc[i][3][r];
        u16* base = dst + (bhQ * 2048 + s) * 128 + 64;
        base[lm]      = f2b((x1a * cs0 - x2a * sn0) * sc);
        base[16 + lm] = f2b((x1b * cs1 - x2b * sn1) * sc);
        base[32 + lm] = f2b((x1a * sn0 + x2a * cs0) * sc);
        base[48 + lm] = f2b((x1b * sn1 + x2b * cs1) * sc);
      }
  } else {
    const int hv0 = (bn - 4096) >> 7;
#pragma unroll
    for (int i = 0; i < 4; ++i)
#pragma unroll
      for (int r = 0; r < 4; ++r) {
        const int sr = wm + i * 16 + quad * 4 + r;  // 0..127
#pragma unroll
        for (int j = 0; j < 4; ++j) {
          const int d = wn + j * 16 + lm;  // 0..255
          sh[d * 128 + (((sr >> 3) ^ (d & 7)) << 3) + (sr & 7)] = f2b(acc[i][j][r]);
        }
      }
    __syncthreads();
#pragma unroll
    for (int it = 0; it < 8; ++it) {
      const int idx = it * 512 + tid;  // 0..4095
      const int d = idx >> 4;          // 0..255
      const int ch = idx & 15;
      bf16x8 v = *(const bf16x8*)(sh + d * 128 + ((ch ^ (d & 7)) << 3));
      const size_t bh = (size_t)b * 16 + hv0 + (d >> 7);
      *(bf16x8*)(VT + (bh * 128 + (d & 127)) * 2048 + sbase + ch * 8) = v;
    }
  }
}

// ---------------- final projection: 128x256 8-phase, fp32 out -----------------
// Same schedule as gemm_qkv8 (twice-verified); grid 8x32 = 256 blocks =
// exactly 1.0 dispatch round at 1 block/CU. Epilogue: direct fp32 stores
// (the proven gemm_bt pattern; (i>>1)*32+(i&1)*16 == i*16 so the acc->row
// map is the identity transplant).
__global__ __launch_bounds__(512, 2) void gemm_out8(const u16* __restrict__ A,
                                                    const u16* __restrict__ B,
                                                    float* __restrict__ C) {
  constexpr int K = 2048;
  constexpr int N = 2048;
  extern __shared__ u16 sh[];    // 96KB: sA 2x8192 u16 | sB 2x16384 u16
  u16* sA = sh;
  u16* sB = sh + 16384;
  const int tid = threadIdx.x;
  const int wid = tid >> 6, lane = tid & 63;
  const int lm = lane & 15, quad = lane >> 4, rx = lm & 7;
  const int wm = (wid >> 2) * 64;
  const int wn = (wid & 3) * 64;
  const int bm = blockIdx.y * 128;
  const int bn = blockIdx.x * 256;
  const u16* Ablk = A + (size_t)bm * K;
  const u16* Bblk = B + (size_t)bn * K;

  f32x4 zero = {0.f, 0.f, 0.f, 0.f};
  f32x4 acc[4][4];
#pragma unroll
  for (int i = 0; i < 4; ++i)
#pragma unroll
    for (int j = 0; j < 4; ++j) acc[i][j] = zero;

  bf16x8 aA[2][2];
  bf16x8 bB[2][2][2];

  auto stageu = [&](int st, int ut) {
    const int k0 = st << 6;
    const int bf = st & 1;
    const u16* src;
    u16* dst;
    int rowbase;
    if (ut == 0) { src = Ablk; rowbase = 0; dst = sA + bf * 8192; }
    else { src = Bblk; rowbase = (ut - 1) << 7; dst = sB + bf * 16384 + ((ut - 1) << 13); }
#pragma unroll
    for (int it = 0; it < 2; ++it) {
      const int c = it * 512 + tid;
      const int r = c >> 3, u = c & 7;
      g2l16(src + (size_t)(rowbase + r) * K + k0 + ((u ^ (r & 7)) << 3), dst + (size_t)c * 8);
    }
  };
  auto ldA = [&](int bf, int mh) {
    const u16* base = sA + bf * 8192;
#pragma unroll
    for (int ii = 0; ii < 2; ++ii)
#pragma unroll
      for (int ks = 0; ks < 2; ++ks) {
        const int row = wm + mh * 32 + ii * 16 + lm;
        aA[ii][ks] = *(const bf16x8*)(base + ((row * 8 + ((ks * 4 + quad) ^ rx)) << 3));
      }
  };
  auto ldB = [&](int bf, int nh) {
    const u16* base = sB + bf * 16384;
#pragma unroll
    for (int jj = 0; jj < 2; ++jj)
#pragma unroll
      for (int ks = 0; ks < 2; ++ks) {
        const int row = wn + nh * 32 + jj * 16 + lm;
        bB[nh][jj][ks] = *(const bf16x8*)(base + ((row * 8 + ((ks * 4 + quad) ^ rx)) << 3));
      }
  };
  auto mm = [&](int mh, int nh) {
    __builtin_amdgcn_s_setprio(1);
#pragma unroll
    for (int ii = 0; ii < 2; ++ii)
#pragma unroll
      for (int jj = 0; jj < 2; ++jj)
#pragma unroll
        for (int ks = 0; ks < 2; ++ks)
          acc[mh * 2 + ii][nh * 2 + jj] =
              MFMA32(aA[ii][ks], bB[nh][jj][ks], acc[mh * 2 + ii][nh * 2 + jj]);
    __builtin_amdgcn_s_setprio(0);
  };

  const int NT = K >> 6;
  const int NIT = NT >> 1;

  stageu(0, 0); stageu(0, 1); stageu(0, 2); stageu(1, 0);
  asm volatile("s_waitcnt vmcnt(2)" ::: "memory");
  __builtin_amdgcn_s_barrier();

#pragma unroll 1
  for (int i = 0; i < NIT; ++i) {
    const int t1 = 2 * i + 1, t2 = 2 * i + 2, t3 = 2 * i + 3;
    ldA(0, 0); ldB(0, 0);
    stageu(t1, 1);
    __builtin_amdgcn_s_barrier();
    mm(0, 0);
    __builtin_amdgcn_s_barrier();
    ldB(0, 1);
    stageu(t1, 2);
    __builtin_amdgcn_s_barrier();
    mm(0, 1);
    __builtin_amdgcn_s_barrier();
    ldA(0, 1);
    __builtin_amdgcn_s_barrier();
    mm(1, 1);
    __builtin_amdgcn_s_barrier();
    {
      const bool st = (t2 < NT);
      if (st) stageu(t2, 0);
      __builtin_amdgcn_s_barrier();
      mm(1, 0);
      if (st) asm volatile("s_waitcnt vmcnt(2)" ::: "memory");
      else    asm volatile("s_waitcnt vmcnt(0)" ::: "memory");
      __builtin_amdgcn_s_barrier();
    }
    ldA(1, 0); ldB(1, 0);
    if (t2 < NT) stageu(t2, 1);
    __builtin_amdgcn_s_barrier();
    mm(0, 0);
    __builtin_amdgcn_s_barrier();
    ldB(1, 1);
    if (t2 < NT) stageu(t2, 2);
    __builtin_amdgcn_s_barrier();
    mm(0, 1);
    __builtin_amdgcn_s_barrier();
    ldA(1, 1);
    __builtin_amdgcn_s_barrier();
    mm(1, 1);
    __builtin_amdgcn_s_barrier();
    {
      const bool st = (t3 < NT);
      if (st) stageu(t3, 0);
      __builtin_amdgcn_s_barrier();
      mm(1, 0);
      if (st) asm volatile("s_waitcnt vmcnt(2)" ::: "memory");
      else    asm volatile("s_waitcnt vmcnt(0)" ::: "memory");
      __builtin_amdgcn_s_barrier();
    }
  }

  // epilogue: direct fp32 stores
#pragma unroll
  for (int i = 0; i < 4; ++i)
#pragma unroll
    for (int j = 0; j < 4; ++j)
#pragma unroll
      for (int r = 0; r < 4; ++r) {
        const int row = bm + wm + i * 16 + quad * 4 + r;
        const int col = bn + wn + j * 16 + lm;
        C[(size_t)row * N + col] = acc[i][j][r];
      }
}

// ---------------- fused causal attention v9 (ACCEPTED final) ------------------
__global__ __launch_bounds__(256, 3) void attn_v9(const u16* __restrict__ Q,
                                                  const u16* __restrict__ K,
                                                  const u16* __restrict__ VT,
                                                  u16* __restrict__ O) {
  constexpr int S = 2048;
  constexpr int D = 128;
  __shared__ u16 Ks[64 * 128];  // chunk-swizzled
  __shared__ u16 Vs[128 * 64];  // VT tile [d][s_local], chunk-swizzled
  __shared__ u16 Ps[64 * 72];   // wave-private rows; padded stride 72
  const int linear = blockIdx.x + (blockIdx.y << 4);
  const int xcd = linear & 7;
  const int slot = linear >> 3;          // 0..63
  const int bh = (xcd << 2) + (slot >> 4);
  const int bx = slot & 15;
  const int b = bh >> 4, h = bh & 15;
  const int tid = threadIdx.x, wid = tid >> 6, lane = tid & 63;
  const int lm = lane & 15, quad = lane >> 4;
  const int rx = lm & 7;
  const int wrow = wid * 16;

  const u16* Kbh = K + (size_t)bh * S * D;
  const u16* Vbh = VT + (size_t)bh * D * S;

  const bf16x8 vones = {16256, 16256, 16256, 16256, 16256, 16256, 16256, 16256};  // bf16 1.0

#pragma unroll 1
  for (int pass = 0; pass < 2; ++pass) {
    const int qt = pass == 0 ? bx : 31 - bx;

    bf16x8 aq[4];
#pragma unroll
    for (int ks = 0; ks < 4; ++ks)
      aq[ks] = *(const bf16x8*)(Q + ((size_t)bh * S + (size_t)qt * 64 + wrow + lm) * D +
                                ks * 32 + quad * 8);

    f32x4 zero = {0.f, 0.f, 0.f, 0.f};
    f32x4 lsum = zero;
    f32x4 oacc[8];
#pragma unroll
    for (int t = 0; t < 8; ++t) oacc[t] = zero;

#pragma unroll 1
    for (int kt = 0; kt <= qt; ++kt) {
      __syncthreads();  // prior iteration's readers done with Ks/Vs
      const u16* Kt = Kbh + (size_t)kt * 64 * D;
      const u16* Vt = Vbh + (size_t)kt * 64;
#pragma unroll
      for (int it = 0; it < 4; ++it) {
        int c = it * 256 + tid;
        int row = c >> 4, u = c & 15;
        g2l16(Kt + (size_t)row * 128 + (size_t)(u ^ (row & 7)) * 8, Ks + c * 8);
      }
#pragma unroll
      for (int it = 0; it < 4; ++it) {
        int c = it * 256 + tid;
        int row = c >> 3, u = c & 7;
        g2l16(Vt + (size_t)row * S + (size_t)(u ^ (row & 7)) * 8, Vs + c * 8);
      }
      __syncthreads();  // barrier drains vmcnt: staged data visible

      // S-tile = Q K^T
      f32x4 sc[4];
#pragma unroll
      for (int j = 0; j < 4; ++j) sc[j] = zero;
      __builtin_amdgcn_s_setprio(1);
#pragma unroll
      for (int ks = 0; ks < 4; ++ks) {
        const int kc = ks * 4 + quad;
#pragma unroll
        for (int j = 0; j < 4; ++j) {
          bf16x8 bk = *(const bf16x8*)(Ks + (((j * 16 + lm) * 16 + (kc ^ rx)) * 8));
          sc[j] = MFMA32(aq[ks], bk, sc[j]);
        }
      }
      __builtin_amdgcn_s_setprio(0);

      const bool diag = (kt == qt);
#pragma unroll
      for (int r = 0; r < 4; ++r) {
        const int qcol = wrow + quad * 4 + r;
        const int prow = (wrow + quad * 4 + r) * 72;
#pragma unroll
        for (int j = 0; j < 4; ++j) {
          float p = __builtin_amdgcn_exp2f(fminf(sc[j][r], 30.0f));
          if (diag && (j * 16 + lm > qcol)) p = 0.f;
          Ps[prow + j * 16 + lm] = f2b(p);
        }
      }
      // no barrier: Ps rows are wave-private (proven R4)

      // O += P @ V ; row-sum += P @ ones
      __builtin_amdgcn_s_setprio(1);
#pragma unroll
      for (int ks = 0; ks < 2; ++ks) {
        bf16x8 ap = *(const bf16x8*)(Ps + (wrow + lm) * 72 + ks * 32 + quad * 8);
        const int kc = ks * 4 + quad;
        lsum = MFMA32(ap, vones, lsum);
#pragma unroll
        for (int t = 0; t < 8; ++t) {
          bf16x8 bv = *(const bf16x8*)(Vs + (((t * 16 + lm) * 8 + (kc ^ rx)) * 8));
          oacc[t] = MFMA32(ap, bv, oacc[t]);
        }
      }
      __builtin_amdgcn_s_setprio(0);
    }

#pragma unroll
    for (int r = 0; r < 4; ++r) {
      float inv = 1.0f / lsum[r];
      const int srow = qt * 64 + wrow + quad * 4 + r;
      u16* Orow = O + ((size_t)b * S + srow) * 2048 + h * 128;
#pragma unroll
      for (int t = 0; t < 8; ++t) Orow[t * 16 + lm] = f2b(oacc[t][r] * inv);
    }
  }
}

extern "C" void kernel_launch(void* const* d_in, const int* in_sizes, int n_in,
                              void* d_out, int out_size, void* d_ws, size_t ws_size,
                              hipStream_t stream) {
  const float* x      = (const float*)d_in[0];
  const float* Wq_sem = (const float*)d_in[1];
  const float* Wk_sem = (const float*)d_in[2];
  const float* Wq_geo = (const float*)d_in[3];
  const float* Wk_geo = (const float*)d_in[4];
  const float* Wv     = (const float*)d_in[5];
  const float* Wo     = (const float*)d_in[6];

  char* ws = (char*)d_ws;
  // layout (bytes):
  //   [0, 16M)          xb  (x bf16, 4096x2048)
  //   [16M, 41.2M)      Wall (6144x2048 bf16)   -> later reused as O
  //   [41.2M, 49.6M)    Wob  (2048x2048 bf16)
  //   [49.6M, 66.3M)    Qb   (bf16, 32 heads x 2048 x 128)
  // d_out (33.5MB) used as scratch for K (16.7M) + VT (16.7M) until final GEMM.
  u16* xb   = (u16*)(ws);
  u16* Wall = (u16*)(ws + 16777216);
  u16* Wob  = (u16*)(ws + 16777216 + 25165824);
  u16* Qb   = (u16*)(ws + 16777216 + 25165824 + 8388608);
  u16* Ob   = Wall;
  u16* Kb   = (u16*)d_out;
  u16* VT   = (u16*)((char*)d_out + 16777216);

  hipFuncSetAttribute((const void*)gemm_qkv8,
                      hipFuncAttributeMaxDynamicSharedMemorySize, 98304);
  hipFuncSetAttribute((const void*)gemm_out8,
                      hipFuncAttributeMaxDynamicSharedMemorySize, 98304);

  // all casts in one launch
  cast_all<<<24576, 256, 0, stream>>>(x, Wq_sem, Wk_sem, Wq_geo, Wk_geo, Wv, Wo,
                                      xb, Wall, Wob);

  // fused QKV projection + RoPE + head rearrange: 128x256 8-phase, 768 blocks
  gemm_qkv8<<<dim3(24, 32), 512, 98304, stream>>>(xb, Wall, Qb, Kb, VT);

  // causal flash attention -> O (B*S, 2048) bf16
  attn_v9<<<dim3(16, 32), 256, 0, stream>>>(Qb, Kb, VT, Ob);

  // final projection: out = O @ Wo^T (M=4096, N=2048, K=2048), 256 blocks = 1 round
  gemm_out8<<<dim3(8, 32), 512, 98304, stream>>>(Ob, Wob, (float*)d_out);
}